// Round 9
// baseline (128.719 us; speedup 1.0000x reference)
//
#include <hip/hip_runtime.h>

#define DEV static __device__ __forceinline__

typedef __attribute__((ext_vector_type(8))) short short8;
typedef __attribute__((ext_vector_type(8))) __bf16 bf16x8;
typedef __attribute__((ext_vector_type(4))) float f32x4;

// N=8 agents, B=8192, OBS=128, ACT=32, D=160, E=128, L=8
//
// pi-layout: within each 128-wide k-chunk, position p = 8*g + m holds actual
// k = 16*m + g. Applied consistently to eB, SB, WvP, W1P so MFMA operand
// elements pair correctly; benefit: a lane's 8 C-layout accumulator values
// (cols 16m+lr, m=0..7) form one contiguous 16B granule at (row, granule=lr).
//
// Register-budget law (R5/R6/R8 post-mortems): fused k3 spills to scratch
// whenever simultaneous acc-live > ~96 regs (hacc 64 + one vacc 32 is the
// max). No persistent prefetch regs, no vacc[2][8] B-sharing.

DEV short f2bf(float f) { return __builtin_bit_cast(short, (__bf16)f); }
DEV float bf2f(short h) {
  unsigned u = ((unsigned)(unsigned short)h) << 16;
  return __builtin_bit_cast(float, u);
}
DEV f32x4 mfma16(short8 a, short8 b, f32x4 c) {
  return __builtin_amdgcn_mfma_f32_16x16x32_bf16(
      __builtin_bit_cast(bf16x8, a), __builtin_bit_cast(bf16x8, b), c, 0, 0, 0);
}
DEV void async_copy16(short* lds, const short* g) {
  __builtin_amdgcn_global_load_lds(
      (const __attribute__((address_space(1))) void*)g,
      (__attribute__((address_space(3))) void*)lds, 16, 0, 0);
}

template <int GPC, int SRC_STRIDE, int LDS_STRIDE>
DEV void stage_bt(short* lds, const short* src, int tid) {
  constexpr int TOTAL = 128 * GPC;
  #pragma unroll
  for (int g0 = 0; g0 < TOTAL; g0 += 256) {
    int g = g0 + tid;
    int c = g / GPC, kg = g % GPC;
    *(short8*)(lds + c * LDS_STRIDE + kg * 8) =
        *(const short8*)(src + c * SRC_STRIDE + kg * 8);
  }
}

// ---- K0: weights fp32 [K][128] -> bf16 [128][K]; Wv/W1 in pi-k order.
//      c-fastest lane mapping so the fp32 source reads coalesce. ------------
__global__ __launch_bounds__(256) void k0_tr(const float* __restrict__ Wg,
                                             const float* __restrict__ Wv,
                                             const float* __restrict__ W1,
                                             short* __restrict__ WgT,
                                             short* __restrict__ WvP,
                                             short* __restrict__ W1P) {
  int g = blockIdx.x * 256 + threadIdx.x;  // 184320 granules total
  short8 o;
  if (g < 20480) {  // Wg: 8 x 20kg x 128c, K=160, natural k
    int n = g / 2560, rem = g % 2560;
    int c = rem & 127, kg = rem >> 7;
    const float* src = Wg + n * 20480;
    #pragma unroll
    for (int j = 0; j < 8; ++j) o[j] = f2bf(src[(size_t)(kg * 8 + j) * 128 + c]);
    *(short8*)(WgT + n * 20480 + c * 160 + kg * 8) = o;
  } else if (g < 36864) {  // Wv: 8 x 16kg x 128c, K=128, pi order
    int g2 = g - 20480;
    int n = g2 >> 11, rem = g2 & 2047;
    int c = rem & 127, kg = rem >> 7;
    const float* src = Wv + n * 16384;
    #pragma unroll
    for (int j = 0; j < 8; ++j) o[j] = f2bf(src[(size_t)(16 * j + kg) * 128 + c]);
    *(short8*)(WvP + n * 16384 + c * 128 + kg * 8) = o;
  } else {  // W1: 8 x 144kg x 128c, K=1152, pi order within each 128-chunk
    int g3 = g - 36864;
    int n = g3 / 18432, rem = g3 % 18432;
    int c = rem & 127, kg = rem >> 7;
    int chunk = kg >> 4, kl = kg & 15;
    const float* src = W1 + (size_t)n * 147456;
    #pragma unroll
    for (int j = 0; j < 8; ++j)
      o[j] = f2bf(src[(size_t)(chunk * 128 + 16 * j + kl) * 128 + c]);
    *(short8*)(W1P + (size_t)n * 147456 + c * 1152 + kg * 8) = o;
  }
}

// ---- K1: e = relu(oa @ Wg + bg) -> bf16, pi-packed granule stores ----------
__global__ __launch_bounds__(256) void k1_e(const float* __restrict__ obs,
                                            const float* __restrict__ act,
                                            const short* __restrict__ WgT,
                                            const float* __restrict__ bg,
                                            short* __restrict__ eB) {
  __shared__ __align__(16) short BW[128 * 168];
  const int btile = blockIdx.x, n = blockIdx.y, tid = threadIdx.x;
  stage_bt<20, 160, 168>(BW, WgT + n * 20480, tid);
  __syncthreads();
  const int lane = tid & 63, wave = tid >> 6, lr = lane & 15, kg = lane >> 4;
  const int rowbase = btile * 64 + wave * 16;
  f32x4 acc[8];
  #pragma unroll
  for (int m = 0; m < 8; ++m) acc[m] = f32x4{0.f, 0.f, 0.f, 0.f};
  const float* obsp = obs + (size_t)(n * 8192 + rowbase + lr) * 128;
  const float* actp = act + (size_t)(n * 8192 + rowbase + lr) * 32;
  #pragma unroll
  for (int ks = 0; ks < 5; ++ks) {
    const float* ap = (ks < 4) ? (obsp + ks * 32 + kg * 8) : (actp + kg * 8);
    float4 p0 = *(const float4*)ap;
    float4 p1 = *(const float4*)(ap + 4);
    short8 a;
    a[0] = f2bf(p0.x); a[1] = f2bf(p0.y); a[2] = f2bf(p0.z); a[3] = f2bf(p0.w);
    a[4] = f2bf(p1.x); a[5] = f2bf(p1.y); a[6] = f2bf(p1.z); a[7] = f2bf(p1.w);
    #pragma unroll
    for (int m = 0; m < 8; ++m) {
      short8 b = *(const short8*)(&BW[(m * 16 + lr) * 168 + ks * 32 + kg * 8]);
      acc[m] = mfma16(a, b, acc[m]);
    }
  }
  float bgv[8];
  #pragma unroll
  for (int m = 0; m < 8; ++m) bgv[m] = bg[n * 128 + m * 16 + lr];
  #pragma unroll
  for (int r = 0; r < 4; ++r) {
    short8 pkt;
    #pragma unroll
    for (int m = 0; m < 8; ++m) {
      float x = acc[m][r] + bgv[m];
      pkt[m] = f2bf(x > 0.f ? x : 0.f);
    }
    *(short8*)(eB + (size_t)(n * 8192 + rowbase + kg * 4 + r) * 128 + lr * 8) = pkt;
  }
}

// ---- K2: S[l] = sum_j leaky(e[j] @ Wv[l] + bv[l]) -> bf16, pi-packed -------
__global__ __launch_bounds__(256) void k2_S(const short* __restrict__ eB,
                                            const short* __restrict__ WvP,
                                            const float* __restrict__ bv,
                                            short* __restrict__ SB) {
  __shared__ __align__(16) short BW[128 * 136];
  const int btile = blockIdx.x, l = blockIdx.y, tid = threadIdx.x;
  stage_bt<16, 128, 136>(BW, WvP + l * 16384, tid);
  __syncthreads();
  const int lane = tid & 63, wave = tid >> 6, lr = lane & 15, kg = lane >> 4;
  const int rowbase = btile * 64 + wave * 16;
  f32x4 Sacc[8];
  #pragma unroll
  for (int m = 0; m < 8; ++m) Sacc[m] = f32x4{0.f, 0.f, 0.f, 0.f};
  float bvv[8];
  #pragma unroll
  for (int m = 0; m < 8; ++m) bvv[m] = bv[l * 128 + m * 16 + lr];
  for (int j = 0; j < 8; ++j) {
    f32x4 acc[8];
    #pragma unroll
    for (int m = 0; m < 8; ++m) acc[m] = f32x4{0.f, 0.f, 0.f, 0.f};
    const short* ep = eB + (size_t)(j * 8192 + rowbase + lr) * 128;
    #pragma unroll
    for (int ks = 0; ks < 4; ++ks) {
      short8 a = *(const short8*)(ep + ks * 32 + kg * 8);
      #pragma unroll
      for (int m = 0; m < 8; ++m) {
        short8 b = *(const short8*)(&BW[(m * 16 + lr) * 136 + ks * 32 + kg * 8]);
        acc[m] = mfma16(a, b, acc[m]);
      }
    }
    #pragma unroll
    for (int m = 0; m < 8; ++m)
      #pragma unroll
      for (int r = 0; r < 4; ++r) {
        float x = acc[m][r] + bvv[m];
        Sacc[m][r] += (x > 0.f ? x : 0.01f * x);
      }
  }
  #pragma unroll
  for (int r = 0; r < 4; ++r) {
    short8 pkt;
    #pragma unroll
    for (int m = 0; m < 8; ++m) pkt[m] = f2bf(Sacc[m][r]);
    *(short8*)(SB + (size_t)(l * 8192 + rowbase + kg * 4 + r) * 128 + lr * 8) = pkt;
  }
}

// ---- K3: fused 17-chunk GEMM, 256 rows/block, 8 waves, agent->XCD pinned.
//      h = relu(sum_l (S_l - v_{l,i})@W1_l + e@W1e + b1); out = h.W2 + b2.
//      R9 = R7 structure (per-s vacc[8], no B-share => no spill) + R8's SBuf
//      staging (S_l via global_load_lds, sv becomes an LDS read).
__global__ __launch_bounds__(512, 2) void k3_f(const short* __restrict__ eB,
                                               const short* __restrict__ SB,
                                               const short* __restrict__ WvP,
                                               const short* __restrict__ W1P,
                                               const float* __restrict__ bv,
                                               const float* __restrict__ b1,
                                               const float* __restrict__ W2,
                                               const float* __restrict__ b2,
                                               float* __restrict__ out) {
  __shared__ __align__(16) short BW[2][128 * 128];  // 64 KB dbuf (weights)
  __shared__ __align__(16) short SBuf[256 * 128];   // 64 KB, S_l rows of block
  __shared__ __align__(16) short VB[8][8 * 128];    // 16 KB, per-wave slices
  const int bid = blockIdx.x;
  const int i = bid & 7;        // agent -> XCD pinning (round-robin dispatch)
  const int btile = bid >> 3;   // 32 btiles x 256 rows
  const int tid = threadIdx.x;
  const int lane = tid & 63, wave = tid >> 6, lr = lane & 15, kg = lane >> 4;
  const int lr8 = lane & 7;
  const int rowbase = btile * 256 + wave * 32;
  const short* w1 = W1P + (size_t)i * 147456;
  short* vb = VB[wave];

#define STAGE_WV(buf, l)                                                       \
  {                                                                            \
    _Pragma("unroll") for (int t = 0; t < 4; ++t) {                            \
      int G = t * 512 + tid;                                                   \
      int cG = G >> 4, gl = G & 15;                                            \
      async_copy16((buf) + (t * 512 + wave * 64) * 8,                          \
                   WvP + (l) * 16384 + cG * 128 + ((gl ^ (cG & 7)) << 3));     \
    }                                                                          \
  }
#define STAGE_W1(buf, koff)                                                    \
  {                                                                            \
    _Pragma("unroll") for (int t = 0; t < 4; ++t) {                            \
      int G = t * 512 + tid;                                                   \
      int cG = G >> 4, gl = G & 15;                                            \
      async_copy16((buf) + (t * 512 + wave * 64) * 8,                          \
                   w1 + cG * 1152 + (koff) + ((gl ^ (cG & 7)) << 3));          \
    }                                                                          \
  }
// S_l rows [btile*256, +256) -> SBuf linear [row][128] (pi granules match)
#define STAGE_SB(l)                                                            \
  {                                                                            \
    _Pragma("unroll") for (int t = 0; t < 8; ++t) {                            \
      int G = t * 512 + tid;                                                   \
      int row = G >> 4, gl = G & 15;                                           \
      async_copy16(SBuf + (t * 512 + wave * 64) * 8,                           \
                   SB + ((size_t)(l) * 8192 + btile * 256 + row) * 128 +       \
                       gl * 8);                                                \
    }                                                                          \
  }

  short8 ea[2][4];
  #pragma unroll
  for (int s = 0; s < 2; ++s)
    #pragma unroll
    for (int ks = 0; ks < 4; ++ks)
      ea[s][ks] = *(const short8*)(
          eB + (size_t)(i * 8192 + rowbase + s * 16 + lr) * 128 + (ks * 4 + kg) * 8);

  f32x4 hacc[2][8];
  #pragma unroll
  for (int s = 0; s < 2; ++s)
    #pragma unroll
    for (int m = 0; m < 8; ++m) hacc[s][m] = f32x4{0.f, 0.f, 0.f, 0.f};
  short8 aa[2][4];

  STAGE_WV(BW[0], 0);
  STAGE_SB(0);
  for (int c = 0; c < 17; ++c) {
    __syncthreads();  // stage(c) drained; BW[(c+1)&1] (and SBuf at even) ready
    if (c < 16) {
      int nc = c + 1;
      if (nc == 16) { STAGE_W1(BW[0], 1024); }
      else if (nc & 1) { STAGE_W1(BW[1], (nc >> 1) * 128); }
      else { STAGE_WV(BW[0], nc >> 1); STAGE_SB(nc >> 1); }
    }
    const short* bw = BW[c & 1];
    if (c == 16) {  // + e @ W1e
      #pragma unroll
      for (int ks = 0; ks < 4; ++ks)
        #pragma unroll
        for (int m = 0; m < 8; ++m) {
          short8 b = *(const short8*)(bw + (m * 16 + lr) * 128 +
                                      (((ks * 4 + kg) ^ lr8) << 3));
          hacc[0][m] = mfma16(ea[0][ks], b, hacc[0][m]);
          hacc[1][m] = mfma16(ea[1][ks], b, hacc[1][m]);
        }
    } else if (c & 1) {  // W1_l: hacc += (S-v) @ W1_l
      #pragma unroll
      for (int ks = 0; ks < 4; ++ks)
        #pragma unroll
        for (int m = 0; m < 8; ++m) {
          short8 b = *(const short8*)(bw + (m * 16 + lr) * 128 +
                                      (((ks * 4 + kg) ^ lr8) << 3));
          hacc[0][m] = mfma16(aa[0][ks], b, hacc[0][m]);
          hacc[1][m] = mfma16(aa[1][ks], b, hacc[1][m]);
        }
    } else {  // Wv_l: aa = S_l - leaky(e @ Wv_l + bv_l), via VB round-trip
      const int l = c >> 1;
      float bvv[8];
      #pragma unroll
      for (int m = 0; m < 8; ++m) bvv[m] = bv[l * 128 + m * 16 + lr];
      #pragma unroll
      for (int s = 0; s < 2; ++s) {
        f32x4 vacc[8];
        #pragma unroll
        for (int m = 0; m < 8; ++m) vacc[m] = f32x4{0.f, 0.f, 0.f, 0.f};
        #pragma unroll
        for (int ks = 0; ks < 4; ++ks)
          #pragma unroll
          for (int m = 0; m < 8; ++m) {
            short8 b = *(const short8*)(bw + (m * 16 + lr) * 128 +
                                        (((ks * 4 + kg) ^ lr8) << 3));
            vacc[m] = mfma16(ea[s][ks], b, vacc[m]);
          }
        short8 pkt[4];
        #pragma unroll
        for (int r = 0; r < 4; ++r) {
          short8 sv = *(const short8*)(
              SBuf + (wave * 32 + s * 16 + kg * 4 + r) * 128 + lr * 8);
          #pragma unroll
          for (int m = 0; m < 8; ++m) {
            float x = vacc[m][r] + bvv[m];
            x = (x > 0.f) ? x : 0.01f * x;   // leaky_relu
            pkt[r][m] = f2bf(bf2f(sv[m]) - x);
          }
        }
        // C->A via 2KB/wave VB in two row-halves (exec-masked):
        // half p: lanes kg in {2p,2p+1} write local rows [0,8); lanes with
        // lr in [8p,8p+8) read their 4 A-fragments. Same-wave DS ordering
        // (compiler lgkmcnt) keeps write->read and half-reuse safe.
        #pragma unroll
        for (int p = 0; p < 2; ++p) {
          if ((kg >> 1) == p) {
            #pragma unroll
            for (int r = 0; r < 4; ++r) {
              int rl = (kg & 1) * 4 + r;
              *(short8*)(vb + rl * 128 + ((lr ^ rl) << 3)) = pkt[r];
            }
          }
          if ((lr >> 3) == p) {
            int rl = lr & 7;
            #pragma unroll
            for (int ks = 0; ks < 4; ++ks)
              aa[s][ks] = *(const short8*)(vb + rl * 128 +
                                           (((ks * 4 + kg) ^ rl) << 3));
          }
        }
      }
    }
  }
#undef STAGE_WV
#undef STAGE_W1
#undef STAGE_SB

  // epilogue: h = relu(hacc + b1); out = h . W2 + b2
  #pragma unroll
  for (int s = 0; s < 2; ++s) {
    float sacc[4] = {0.f, 0.f, 0.f, 0.f};
    #pragma unroll
    for (int m = 0; m < 8; ++m) {
      int col = m * 16 + lr;
      float b1v = b1[i * 128 + col];
      float w2v = W2[i * 128 + col];
      #pragma unroll
      for (int r = 0; r < 4; ++r) {
        float h = hacc[s][m][r] + b1v;
        h = h > 0.f ? h : 0.f;
        sacc[r] += h * w2v;
      }
    }
    #pragma unroll
    for (int r = 0; r < 4; ++r) {
      float v = sacc[r];
      v += __shfl_xor(v, 1);
      v += __shfl_xor(v, 2);
      v += __shfl_xor(v, 4);
      v += __shfl_xor(v, 8);
      if (lr == 0)
        out[i * 8192 + rowbase + s * 16 + kg * 4 + r] = v + b2[i];
    }
  }
}

extern "C" void kernel_launch(void* const* d_in, const int* in_sizes, int n_in,
                              void* d_out, int out_size, void* d_ws, size_t ws_size,
                              hipStream_t stream) {
  const float* obs = (const float*)d_in[0];
  const float* act = (const float*)d_in[1];
  const float* Wg  = (const float*)d_in[2];
  const float* bg  = (const float*)d_in[3];
  // d_in[4..7] = Wq,bq,Wk,bk: dead (softmax over singleton axis == 1)
  const float* Wv  = (const float*)d_in[8];
  const float* bv  = (const float*)d_in[9];
  const float* W1  = (const float*)d_in[10];
  const float* b1  = (const float*)d_in[11];
  const float* W2  = (const float*)d_in[12];
  const float* b2  = (const float*)d_in[13];
  float* out = (float*)d_out;

  // workspace (bf16 shorts): eB 8.4M, SB 8.4M, WgT 163840, WvP 131072, W1P 1179648
  short* eB  = (short*)d_ws;
  short* SB  = eB + (size_t)8 * 8192 * 128;
  short* WgT = SB + (size_t)8 * 8192 * 128;
  short* WvP = WgT + 163840;
  short* W1P = WvP + 131072;

  k0_tr<<<720, 256, 0, stream>>>(Wg, Wv, W1, WgT, WvP, W1P);
  k1_e<<<dim3(128, 8), 256, 0, stream>>>(obs, act, WgT, bg, eB);
  k2_S<<<dim3(128, 8), 256, 0, stream>>>(eB, WvP, bv, SB);
  k3_f<<<256, 512, 0, stream>>>(eB, SB, WvP, W1P, bv, b1, W2, b2, out);
}

// Round 10
// 111.973 us; speedup vs baseline: 1.1496x; 1.1496x over previous
//
#include <hip/hip_runtime.h>

#define DEV static __device__ __forceinline__

typedef __attribute__((ext_vector_type(8))) short short8;
typedef __attribute__((ext_vector_type(8))) __bf16 bf16x8;
typedef __attribute__((ext_vector_type(4))) float f32x4;

// N=8 agents, B=8192, OBS=128, ACT=32, D=160, E=128, L=8
//
// pi-layout: within each 128-wide k-chunk, position p = 8*g + m holds actual
// k = 16*m + g (consistently on both MFMA operands). A lane's 8 C-layout
// accumulator values (cols 16m+lr) form one contiguous 16B granule.
//
// Register law (R5/R6/R8/R9): any k3 structure with >96 simultaneous acc-live
// or >~120 arch-live spills. The split pipeline below keeps k3 at ~80 arch.

DEV short f2bf(float f) { return __builtin_bit_cast(short, (__bf16)f); }
DEV float bf2f(short h) {
  unsigned u = ((unsigned)(unsigned short)h) << 16;
  return __builtin_bit_cast(float, u);
}
DEV f32x4 mfma16(short8 a, short8 b, f32x4 c) {
  return __builtin_amdgcn_mfma_f32_16x16x32_bf16(
      __builtin_bit_cast(bf16x8, a), __builtin_bit_cast(bf16x8, b), c, 0, 0, 0);
}
DEV void async_copy16(short* lds, const short* g) {
  __builtin_amdgcn_global_load_lds(
      (const __attribute__((address_space(1))) void*)g,
      (__attribute__((address_space(3))) void*)lds, 16, 0, 0);
}

template <int GPC, int SRC_STRIDE, int LDS_STRIDE>
DEV void stage_bt(short* lds, const short* src, int tid) {
  constexpr int TOTAL = 128 * GPC;
  #pragma unroll
  for (int g0 = 0; g0 < TOTAL; g0 += 256) {
    int g = g0 + tid;
    int c = g / GPC, kg = g % GPC;
    *(short8*)(lds + c * LDS_STRIDE + kg * 8) =
        *(const short8*)(src + c * SRC_STRIDE + kg * 8);
  }
}

// ---- K0: weights fp32 [K][128] -> bf16 [128][K]; Wv/W1 in pi-k order -------
__global__ __launch_bounds__(256) void k0_tr(const float* __restrict__ Wg,
                                             const float* __restrict__ Wv,
                                             const float* __restrict__ W1,
                                             short* __restrict__ WgT,
                                             short* __restrict__ WvP,
                                             short* __restrict__ W1P) {
  int g = blockIdx.x * 256 + threadIdx.x;  // 184320 granules total
  short8 o;
  if (g < 20480) {  // Wg: K=160, natural k
    int n = g / 2560, rem = g % 2560;
    int c = rem & 127, kg = rem >> 7;
    const float* src = Wg + n * 20480;
    #pragma unroll
    for (int j = 0; j < 8; ++j) o[j] = f2bf(src[(size_t)(kg * 8 + j) * 128 + c]);
    *(short8*)(WgT + n * 20480 + c * 160 + kg * 8) = o;
  } else if (g < 36864) {  // Wv: K=128, pi order
    int g2 = g - 20480;
    int n = g2 >> 11, rem = g2 & 2047;
    int c = rem & 127, kg = rem >> 7;
    const float* src = Wv + n * 16384;
    #pragma unroll
    for (int j = 0; j < 8; ++j) o[j] = f2bf(src[(size_t)(16 * j + kg) * 128 + c]);
    *(short8*)(WvP + n * 16384 + c * 128 + kg * 8) = o;
  } else {  // W1: K=1152, pi order within each 128-chunk
    int g3 = g - 36864;
    int n = g3 / 18432, rem = g3 % 18432;
    int c = rem & 127, kg = rem >> 7;
    int chunk = kg >> 4, kl = kg & 15;
    const float* src = W1 + (size_t)n * 147456;
    #pragma unroll
    for (int j = 0; j < 8; ++j)
      o[j] = f2bf(src[(size_t)(chunk * 128 + 16 * j + kl) * 128 + c]);
    *(short8*)(W1P + (size_t)n * 147456 + c * 1152 + kg * 8) = o;
  }
}

// ---- K1: e = relu(oa @ Wg + bg) -> bf16, pi-packed granule stores ----------
__global__ __launch_bounds__(256) void k1_e(const float* __restrict__ obs,
                                            const float* __restrict__ act,
                                            const short* __restrict__ WgT,
                                            const float* __restrict__ bg,
                                            short* __restrict__ eB) {
  __shared__ __align__(16) short BW[128 * 168];
  const int btile = blockIdx.x, n = blockIdx.y, tid = threadIdx.x;
  stage_bt<20, 160, 168>(BW, WgT + n * 20480, tid);
  __syncthreads();
  const int lane = tid & 63, wave = tid >> 6, lr = lane & 15, kg = lane >> 4;
  const int rowbase = btile * 64 + wave * 16;
  f32x4 acc[8];
  #pragma unroll
  for (int m = 0; m < 8; ++m) acc[m] = f32x4{0.f, 0.f, 0.f, 0.f};
  const float* obsp = obs + (size_t)(n * 8192 + rowbase + lr) * 128;
  const float* actp = act + (size_t)(n * 8192 + rowbase + lr) * 32;
  #pragma unroll
  for (int ks = 0; ks < 5; ++ks) {
    const float* ap = (ks < 4) ? (obsp + ks * 32 + kg * 8) : (actp + kg * 8);
    float4 p0 = *(const float4*)ap;
    float4 p1 = *(const float4*)(ap + 4);
    short8 a;
    a[0] = f2bf(p0.x); a[1] = f2bf(p0.y); a[2] = f2bf(p0.z); a[3] = f2bf(p0.w);
    a[4] = f2bf(p1.x); a[5] = f2bf(p1.y); a[6] = f2bf(p1.z); a[7] = f2bf(p1.w);
    #pragma unroll
    for (int m = 0; m < 8; ++m) {
      short8 b = *(const short8*)(&BW[(m * 16 + lr) * 168 + ks * 32 + kg * 8]);
      acc[m] = mfma16(a, b, acc[m]);
    }
  }
  float bgv[8];
  #pragma unroll
  for (int m = 0; m < 8; ++m) bgv[m] = bg[n * 128 + m * 16 + lr];
  #pragma unroll
  for (int r = 0; r < 4; ++r) {
    short8 pkt;
    #pragma unroll
    for (int m = 0; m < 8; ++m) {
      float x = acc[m][r] + bgv[m];
      pkt[m] = f2bf(x > 0.f ? x : 0.f);
    }
    *(short8*)(eB + (size_t)(n * 8192 + rowbase + kg * 4 + r) * 128 + lr * 8) = pkt;
  }
}

// ---- K2A: per (btile,l): pass1 S = sum_j leaky(e_j@Wv_l+bv_l) in regs;
//      pass2 recompute v_j, store A = S - v_j as pi-packed b128 granules.
__global__ __launch_bounds__(256) void k2_A(const short* __restrict__ eB,
                                            const short* __restrict__ WvP,
                                            const float* __restrict__ bv,
                                            short* __restrict__ AB) {
  __shared__ __align__(16) short BW[128 * 136];
  const int btile = blockIdx.x, l = blockIdx.y, tid = threadIdx.x;
  stage_bt<16, 128, 136>(BW, WvP + l * 16384, tid);
  __syncthreads();
  const int lane = tid & 63, wave = tid >> 6, lr = lane & 15, kg = lane >> 4;
  const int rowbase = btile * 64 + wave * 16;
  float bvv[8];
  #pragma unroll
  for (int m = 0; m < 8; ++m) bvv[m] = bv[l * 128 + m * 16 + lr];
  f32x4 Sacc[8];
  #pragma unroll
  for (int m = 0; m < 8; ++m) Sacc[m] = f32x4{0.f, 0.f, 0.f, 0.f};
  // pass 1: accumulate S
  for (int j = 0; j < 8; ++j) {
    f32x4 acc[8];
    #pragma unroll
    for (int m = 0; m < 8; ++m) acc[m] = f32x4{0.f, 0.f, 0.f, 0.f};
    const short* ep = eB + (size_t)(j * 8192 + rowbase + lr) * 128;
    #pragma unroll
    for (int ks = 0; ks < 4; ++ks) {
      short8 a = *(const short8*)(ep + ks * 32 + kg * 8);
      #pragma unroll
      for (int m = 0; m < 8; ++m) {
        short8 b = *(const short8*)(&BW[(m * 16 + lr) * 136 + ks * 32 + kg * 8]);
        acc[m] = mfma16(a, b, acc[m]);
      }
    }
    #pragma unroll
    for (int m = 0; m < 8; ++m)
      #pragma unroll
      for (int r = 0; r < 4; ++r) {
        float x = acc[m][r] + bvv[m];
        Sacc[m][r] += (x > 0.f ? x : 0.01f * x);
      }
  }
  // pass 2: recompute v_j, store A = S - v_j (pi granule: one b128 per (r))
  for (int j = 0; j < 8; ++j) {
    f32x4 acc[8];
    #pragma unroll
    for (int m = 0; m < 8; ++m) acc[m] = f32x4{0.f, 0.f, 0.f, 0.f};
    const short* ep = eB + (size_t)(j * 8192 + rowbase + lr) * 128;
    #pragma unroll
    for (int ks = 0; ks < 4; ++ks) {
      short8 a = *(const short8*)(ep + ks * 32 + kg * 8);
      #pragma unroll
      for (int m = 0; m < 8; ++m) {
        short8 b = *(const short8*)(&BW[(m * 16 + lr) * 136 + ks * 32 + kg * 8]);
        acc[m] = mfma16(a, b, acc[m]);
      }
    }
    #pragma unroll
    for (int r = 0; r < 4; ++r) {
      short8 pkt;
      #pragma unroll
      for (int m = 0; m < 8; ++m) {
        float x = acc[m][r] + bvv[m];
        x = (x > 0.f) ? x : 0.01f * x;  // leaky_relu
        pkt[m] = f2bf(Sacc[m][r] - x);
      }
      *(short8*)(AB + (size_t)(j * 8192 + rowbase + kg * 4 + r) * 1024 +
                 l * 128 + lr * 8) = pkt;
    }
  }
}

// ---- K3G: per agent, streaming GEMM h = relu([A_i,e_i]@W1[i]+b1);
//      out = h.W2 + b2. 128 rows/block, 8 waves x 16 rows, grid 512,
//      XCD-pinned, A prefetched one chunk ahead (16 VGPR), W1 dbuf LDS.
__global__ __launch_bounds__(512, 2) void k3_g(const short* __restrict__ eB,
                                               const short* __restrict__ AB,
                                               const short* __restrict__ W1P,
                                               const float* __restrict__ b1,
                                               const float* __restrict__ W2,
                                               const float* __restrict__ b2,
                                               float* __restrict__ out) {
  __shared__ __align__(16) short BW[2][128 * 128];  // 64 KB dbuf -> 2 blk/CU
  const int bid = blockIdx.x;
  const int i = bid & 7;        // agent -> XCD pinning
  const int btile = bid >> 3;   // 64 btiles x 128 rows
  const int tid = threadIdx.x;
  const int lane = tid & 63, wave = tid >> 6, lr = lane & 15, kg = lane >> 4;
  const int lr8 = lane & 7;
  const int rowbase = btile * 128 + wave * 16;
  const short* w1 = W1P + (size_t)i * 147456;

#define STAGE_W1(buf, koff)                                                    \
  {                                                                            \
    _Pragma("unroll") for (int t = 0; t < 4; ++t) {                            \
      int G = t * 512 + tid;                                                   \
      int cG = G >> 4, gl = G & 15;                                            \
      async_copy16((buf) + (t * 512 + wave * 64) * 8,                          \
                   w1 + cG * 1152 + (koff) + ((gl ^ (cG & 7)) << 3));          \
    }                                                                          \
  }

  const short* abase = AB + (size_t)(i * 8192 + rowbase + lr) * 1024;
  const short* ebase = eB + (size_t)(i * 8192 + rowbase + lr) * 128;

  short8 ea[4], aa[4], aap[4];
  #pragma unroll
  for (int ks = 0; ks < 4; ++ks) {
    ea[ks] = *(const short8*)(ebase + (ks * 4 + kg) * 8);
    aa[ks] = *(const short8*)(abase + (ks * 4 + kg) * 8);  // chunk 0
  }
  f32x4 hacc[8];
  #pragma unroll
  for (int m = 0; m < 8; ++m) hacc[m] = f32x4{0.f, 0.f, 0.f, 0.f};

  STAGE_W1(BW[0], 0);
  for (int c = 0; c < 9; ++c) {
    __syncthreads();  // stage(c) drained; BW[(c+1)&1] free
    if (c < 8) { STAGE_W1(BW[(c + 1) & 1], (c + 1 == 8) ? 1024 : (c + 1) * 128); }
    if (c + 1 < 8) {  // prefetch next A chunk
      #pragma unroll
      for (int ks = 0; ks < 4; ++ks)
        aap[ks] = *(const short8*)(abase + (c + 1) * 128 + (ks * 4 + kg) * 8);
    }
    const short* bw = BW[c & 1];
    #pragma unroll
    for (int ks = 0; ks < 4; ++ks)
      #pragma unroll
      for (int m = 0; m < 8; ++m) {
        short8 b = *(const short8*)(bw + (m * 16 + lr) * 128 +
                                    (((ks * 4 + kg) ^ lr8) << 3));
        hacc[m] = mfma16(aa[ks], b, hacc[m]);
      }
    if (c + 1 < 8) {
      #pragma unroll
      for (int ks = 0; ks < 4; ++ks) aa[ks] = aap[ks];
    } else {
      #pragma unroll
      for (int ks = 0; ks < 4; ++ks) aa[ks] = ea[ks];
    }
  }
#undef STAGE_W1

  // epilogue: h = relu(hacc + b1); out = h . W2 + b2
  float sacc[4] = {0.f, 0.f, 0.f, 0.f};
  #pragma unroll
  for (int m = 0; m < 8; ++m) {
    int col = m * 16 + lr;
    float b1v = b1[i * 128 + col];
    float w2v = W2[i * 128 + col];
    #pragma unroll
    for (int r = 0; r < 4; ++r) {
      float h = hacc[m][r] + b1v;
      h = h > 0.f ? h : 0.f;
      sacc[r] += h * w2v;
    }
  }
  #pragma unroll
  for (int r = 0; r < 4; ++r) {
    float v = sacc[r];
    v += __shfl_xor(v, 1);
    v += __shfl_xor(v, 2);
    v += __shfl_xor(v, 4);
    v += __shfl_xor(v, 8);
    if (lr == 0) out[i * 8192 + rowbase + kg * 4 + r] = v + b2[i];
  }
}

extern "C" void kernel_launch(void* const* d_in, const int* in_sizes, int n_in,
                              void* d_out, int out_size, void* d_ws, size_t ws_size,
                              hipStream_t stream) {
  const float* obs = (const float*)d_in[0];
  const float* act = (const float*)d_in[1];
  const float* Wg  = (const float*)d_in[2];
  const float* bg  = (const float*)d_in[3];
  // d_in[4..7] = Wq,bq,Wk,bk: dead (softmax over singleton axis == 1)
  const float* Wv  = (const float*)d_in[8];
  const float* bv  = (const float*)d_in[9];
  const float* W1  = (const float*)d_in[10];
  const float* b1  = (const float*)d_in[11];
  const float* W2  = (const float*)d_in[12];
  const float* b2  = (const float*)d_in[13];
  float* out = (float*)d_out;

  // workspace (bf16 shorts), total ~154 MB (proven to fit in R2):
  short* eB  = (short*)d_ws;                    // [8][8192][128]
  short* AB  = eB + (size_t)8 * 8192 * 128;     // [8][8192][1024]
  short* WgT = AB + (size_t)8 * 8192 * 1024;    // [8][128][160]
  short* WvP = WgT + 163840;                    // [8][128][128]
  short* W1P = WvP + 131072;                    // [8][128][1152]

  k0_tr<<<720, 256, 0, stream>>>(Wg, Wv, W1, WgT, WvP, W1P);
  k1_e<<<dim3(128, 8), 256, 0, stream>>>(obs, act, WgT, bg, eB);
  k2_A<<<dim3(128, 8), 256, 0, stream>>>(eB, WvP, bv, AB);
  k3_g<<<512, 512, 0, stream>>>(eB, AB, W1P, b1, W2, b2, out);
}

// Round 11
// 109.946 us; speedup vs baseline: 1.1707x; 1.0184x over previous
//
#include <hip/hip_runtime.h>

#define DEV static __device__ __forceinline__

typedef __attribute__((ext_vector_type(8))) short short8;
typedef __attribute__((ext_vector_type(8))) __bf16 bf16x8;
typedef __attribute__((ext_vector_type(4))) float f32x4;

// N=8 agents, B=8192, OBS=128, ACT=32, D=160, E=128, L=8
//
// pi-layout: within each 128-wide k-chunk, position p = 8*g + m holds actual
// k = 16*m + g (consistently on both MFMA operands). A lane's 8 C-layout
// accumulator values (cols 16m+lr) form one contiguous 16B granule.
//
// Register law (R5-R9): >96 simultaneous acc-live or >~120 arch-live spills.
// Work law (R10): v must be MFMA'd exactly once (34.4 GF); recompute doubles
// the dominant term. S - v subtraction belongs in k3's A-fragment build.

DEV short f2bf(float f) { return __builtin_bit_cast(short, (__bf16)f); }
DEV float bf2f(short h) {
  unsigned u = ((unsigned)(unsigned short)h) << 16;
  return __builtin_bit_cast(float, u);
}
DEV f32x4 mfma16(short8 a, short8 b, f32x4 c) {
  return __builtin_amdgcn_mfma_f32_16x16x32_bf16(
      __builtin_bit_cast(bf16x8, a), __builtin_bit_cast(bf16x8, b), c, 0, 0, 0);
}
DEV void async_copy16(short* lds, const short* g) {
  __builtin_amdgcn_global_load_lds(
      (const __attribute__((address_space(1))) void*)g,
      (__attribute__((address_space(3))) void*)lds, 16, 0, 0);
}
DEV void nt_store8(short* p, short8 v) {
  __builtin_nontemporal_store(v, (short8*)p);
}
DEV short8 nt_load8(const short* p) {
  return __builtin_nontemporal_load((const short8*)p);
}

template <int GPC, int SRC_STRIDE, int LDS_STRIDE>
DEV void stage_bt(short* lds, const short* src, int tid) {
  constexpr int TOTAL = 128 * GPC;
  #pragma unroll
  for (int g0 = 0; g0 < TOTAL; g0 += 256) {
    int g = g0 + tid;
    int c = g / GPC, kg = g % GPC;
    *(short8*)(lds + c * LDS_STRIDE + kg * 8) =
        *(const short8*)(src + c * SRC_STRIDE + kg * 8);
  }
}

// ---- K0: weights fp32 [K][128] -> bf16 [128][K]; Wv/W1 in pi-k order -------
__global__ __launch_bounds__(256) void k0_tr(const float* __restrict__ Wg,
                                             const float* __restrict__ Wv,
                                             const float* __restrict__ W1,
                                             short* __restrict__ WgT,
                                             short* __restrict__ WvP,
                                             short* __restrict__ W1P) {
  int g = blockIdx.x * 256 + threadIdx.x;  // 184320 granules total
  short8 o;
  if (g < 20480) {  // Wg: K=160, natural k
    int n = g / 2560, rem = g % 2560;
    int c = rem & 127, kg = rem >> 7;
    const float* src = Wg + n * 20480;
    #pragma unroll
    for (int j = 0; j < 8; ++j) o[j] = f2bf(src[(size_t)(kg * 8 + j) * 128 + c]);
    *(short8*)(WgT + n * 20480 + c * 160 + kg * 8) = o;
  } else if (g < 36864) {  // Wv: K=128, pi order
    int g2 = g - 20480;
    int n = g2 >> 11, rem = g2 & 2047;
    int c = rem & 127, kg = rem >> 7;
    const float* src = Wv + n * 16384;
    #pragma unroll
    for (int j = 0; j < 8; ++j) o[j] = f2bf(src[(size_t)(16 * j + kg) * 128 + c]);
    *(short8*)(WvP + n * 16384 + c * 128 + kg * 8) = o;
  } else {  // W1: K=1152, pi order within each 128-chunk
    int g3 = g - 36864;
    int n = g3 / 18432, rem = g3 % 18432;
    int c = rem & 127, kg = rem >> 7;
    int chunk = kg >> 4, kl = kg & 15;
    const float* src = W1 + (size_t)n * 147456;
    #pragma unroll
    for (int j = 0; j < 8; ++j)
      o[j] = f2bf(src[(size_t)(chunk * 128 + 16 * j + kl) * 128 + c]);
    *(short8*)(W1P + (size_t)n * 147456 + c * 1152 + kg * 8) = o;
  }
}

// ---- K1: e = relu(oa @ Wg + bg) -> bf16, pi-packed granule stores ----------
__global__ __launch_bounds__(256) void k1_e(const float* __restrict__ obs,
                                            const float* __restrict__ act,
                                            const short* __restrict__ WgT,
                                            const float* __restrict__ bg,
                                            short* __restrict__ eB) {
  __shared__ __align__(16) short BW[128 * 168];
  const int btile = blockIdx.x, n = blockIdx.y, tid = threadIdx.x;
  stage_bt<20, 160, 168>(BW, WgT + n * 20480, tid);
  __syncthreads();
  const int lane = tid & 63, wave = tid >> 6, lr = lane & 15, kg = lane >> 4;
  const int rowbase = btile * 64 + wave * 16;
  f32x4 acc[8];
  #pragma unroll
  for (int m = 0; m < 8; ++m) acc[m] = f32x4{0.f, 0.f, 0.f, 0.f};
  const float* obsp = obs + (size_t)(n * 8192 + rowbase + lr) * 128;
  const float* actp = act + (size_t)(n * 8192 + rowbase + lr) * 32;
  #pragma unroll
  for (int ks = 0; ks < 5; ++ks) {
    const float* ap = (ks < 4) ? (obsp + ks * 32 + kg * 8) : (actp + kg * 8);
    float4 p0 = *(const float4*)ap;
    float4 p1 = *(const float4*)(ap + 4);
    short8 a;
    a[0] = f2bf(p0.x); a[1] = f2bf(p0.y); a[2] = f2bf(p0.z); a[3] = f2bf(p0.w);
    a[4] = f2bf(p1.x); a[5] = f2bf(p1.y); a[6] = f2bf(p1.z); a[7] = f2bf(p1.w);
    #pragma unroll
    for (int m = 0; m < 8; ++m) {
      short8 b = *(const short8*)(&BW[(m * 16 + lr) * 168 + ks * 32 + kg * 8]);
      acc[m] = mfma16(a, b, acc[m]);
    }
  }
  float bgv[8];
  #pragma unroll
  for (int m = 0; m < 8; ++m) bgv[m] = bg[n * 128 + m * 16 + lr];
  #pragma unroll
  for (int r = 0; r < 4; ++r) {
    short8 pkt;
    #pragma unroll
    for (int m = 0; m < 8; ++m) {
      float x = acc[m][r] + bgv[m];
      pkt[m] = f2bf(x > 0.f ? x : 0.f);
    }
    *(short8*)(eB + (size_t)(n * 8192 + rowbase + kg * 4 + r) * 128 + lr * 8) = pkt;
  }
}

// ============== FAST PATH (ws >= 171 MB): v stored once ====================
// K2V: per (btile,l): v_j = leaky(e_j@Wv_l+bv_l) -> VBg[(j*8+l)] (NT, bf16),
//      S = sum_j v_j accumulated in regs -> SB[l] (regular stores, L3-hot).
__global__ __launch_bounds__(256) void k2_V(const short* __restrict__ eB,
                                            const short* __restrict__ WvP,
                                            const float* __restrict__ bv,
                                            short* __restrict__ SB,
                                            short* __restrict__ VBg) {
  __shared__ __align__(16) short BW[128 * 136];
  const int btile = blockIdx.x, l = blockIdx.y, tid = threadIdx.x;
  stage_bt<16, 128, 136>(BW, WvP + l * 16384, tid);
  __syncthreads();
  const int lane = tid & 63, wave = tid >> 6, lr = lane & 15, kg = lane >> 4;
  const int rowbase = btile * 64 + wave * 16;
  float bvv[8];
  #pragma unroll
  for (int m = 0; m < 8; ++m) bvv[m] = bv[l * 128 + m * 16 + lr];
  f32x4 Sacc[8];
  #pragma unroll
  for (int m = 0; m < 8; ++m) Sacc[m] = f32x4{0.f, 0.f, 0.f, 0.f};
  for (int j = 0; j < 8; ++j) {
    f32x4 acc[8];
    #pragma unroll
    for (int m = 0; m < 8; ++m) acc[m] = f32x4{0.f, 0.f, 0.f, 0.f};
    const short* ep = eB + (size_t)(j * 8192 + rowbase + lr) * 128;
    #pragma unroll
    for (int ks = 0; ks < 4; ++ks) {
      short8 a = *(const short8*)(ep + ks * 32 + kg * 8);
      #pragma unroll
      for (int m = 0; m < 8; ++m) {
        short8 b = *(const short8*)(&BW[(m * 16 + lr) * 136 + ks * 32 + kg * 8]);
        acc[m] = mfma16(a, b, acc[m]);
      }
    }
    #pragma unroll
    for (int r = 0; r < 4; ++r) {
      short8 pkt;
      #pragma unroll
      for (int m = 0; m < 8; ++m) {
        float x = acc[m][r] + bvv[m];
        x = (x > 0.f) ? x : 0.01f * x;  // leaky_relu
        Sacc[m][r] += x;
        pkt[m] = f2bf(x);
      }
      nt_store8(VBg + (size_t)((j * 8 + l) * 8192 + rowbase + kg * 4 + r) * 128 +
                    lr * 8,
                pkt);
    }
  }
  #pragma unroll
  for (int r = 0; r < 4; ++r) {
    short8 pkt;
    #pragma unroll
    for (int m = 0; m < 8; ++m) pkt[m] = f2bf(Sacc[m][r]);
    *(short8*)(SB + (size_t)(l * 8192 + rowbase + kg * 4 + r) * 128 + lr * 8) = pkt;
  }
}

// K3H: per agent, streaming GEMM. Chunk l: A-frag = bf16(S_l) - bf16(v_{l,i})
//      built from prefetched sv (L3) + vv (HBM, NT) loads; chunk 8: e@W1e.
//      hacc 32 acc; sv/vv 32 arch (e-frags reuse sv at c=7) => no spill.
__global__ __launch_bounds__(512, 2) void k3_h(const short* __restrict__ eB,
                                               const short* __restrict__ SB,
                                               const short* __restrict__ VBg,
                                               const short* __restrict__ W1P,
                                               const float* __restrict__ b1,
                                               const float* __restrict__ W2,
                                               const float* __restrict__ b2,
                                               float* __restrict__ out) {
  __shared__ __align__(16) short BW[2][128 * 128];  // 64 KB dbuf -> 2 blk/CU
  const int bid = blockIdx.x;
  const int i = bid & 7;        // agent -> XCD pinning
  const int btile = bid >> 3;   // 64 btiles x 128 rows
  const int tid = threadIdx.x;
  const int lane = tid & 63, wave = tid >> 6, lr = lane & 15, kg = lane >> 4;
  const int lr8 = lane & 7;
  const int rowbase = btile * 128 + wave * 16;
  const short* w1 = W1P + (size_t)i * 147456;

#define STAGE_W1(buf, koff)                                                    \
  {                                                                            \
    _Pragma("unroll") for (int t = 0; t < 4; ++t) {                            \
      int G = t * 512 + tid;                                                   \
      int cG = G >> 4, gl = G & 15;                                            \
      async_copy16((buf) + (t * 512 + wave * 64) * 8,                          \
                   w1 + cG * 1152 + (koff) + ((gl ^ (cG & 7)) << 3));          \
    }                                                                          \
  }

  const short* sbase = SB + (size_t)(rowbase + lr) * 128;          // +l*8192*128
  const short* vbase = VBg + (size_t)((i * 8) * 8192 + rowbase + lr) * 128;

  short8 sv[4], vv[4];
  #pragma unroll
  for (int ks = 0; ks < 4; ++ks) {  // prefetch chunk 0 operands
    sv[ks] = *(const short8*)(sbase + (ks * 4 + kg) * 8);
    vv[ks] = nt_load8(vbase + (ks * 4 + kg) * 8);
  }
  f32x4 hacc[8];
  #pragma unroll
  for (int m = 0; m < 8; ++m) hacc[m] = f32x4{0.f, 0.f, 0.f, 0.f};

  STAGE_W1(BW[0], 0);
  for (int c = 0; c < 9; ++c) {
    __syncthreads();  // stage(c) drained; BW[(c+1)&1] free
    if (c < 8) { STAGE_W1(BW[(c + 1) & 1], (c + 1 == 8) ? 1024 : (c + 1) * 128); }
    short8 aa[4];
    if (c < 8) {
      #pragma unroll
      for (int ks = 0; ks < 4; ++ks)
        #pragma unroll
        for (int jj = 0; jj < 8; ++jj)
          aa[ks][jj] = f2bf(bf2f(sv[ks][jj]) - bf2f(vv[ks][jj]));
      if (c + 1 < 8) {  // prefetch next chunk's S and v fragments
        #pragma unroll
        for (int ks = 0; ks < 4; ++ks) {
          sv[ks] = *(const short8*)(sbase + (size_t)(c + 1) * 8192 * 128 +
                                    (ks * 4 + kg) * 8);
          vv[ks] = nt_load8(vbase + (size_t)(c + 1) * 8192 * 128 +
                            (ks * 4 + kg) * 8);
        }
      } else {  // load e-frags into sv for the final chunk
        #pragma unroll
        for (int ks = 0; ks < 4; ++ks)
          sv[ks] = *(const short8*)(
              eB + (size_t)(i * 8192 + rowbase + lr) * 128 + (ks * 4 + kg) * 8);
      }
    } else {
      #pragma unroll
      for (int ks = 0; ks < 4; ++ks) aa[ks] = sv[ks];  // e fragments
    }
    const short* bw = BW[c & 1];
    #pragma unroll
    for (int ks = 0; ks < 4; ++ks)
      #pragma unroll
      for (int m = 0; m < 8; ++m) {
        short8 b = *(const short8*)(bw + (m * 16 + lr) * 128 +
                                    (((ks * 4 + kg) ^ lr8) << 3));
        hacc[m] = mfma16(aa[ks], b, hacc[m]);
      }
  }
#undef STAGE_W1

  // epilogue: h = relu(hacc + b1); out = h . W2 + b2
  float sacc[4] = {0.f, 0.f, 0.f, 0.f};
  #pragma unroll
  for (int m = 0; m < 8; ++m) {
    int col = m * 16 + lr;
    float b1v = b1[i * 128 + col];
    float w2v = W2[i * 128 + col];
    #pragma unroll
    for (int r = 0; r < 4; ++r) {
      float h = hacc[m][r] + b1v;
      h = h > 0.f ? h : 0.f;
      sacc[r] += h * w2v;
    }
  }
  #pragma unroll
  for (int r = 0; r < 4; ++r) {
    float v = sacc[r];
    v += __shfl_xor(v, 1);
    v += __shfl_xor(v, 2);
    v += __shfl_xor(v, 4);
    v += __shfl_xor(v, 8);
    if (lr == 0) out[i * 8192 + rowbase + kg * 4 + r] = v + b2[i];
  }
}

// ============== FALLBACK PATH (ws < 171 MB): R10 structure =================
__global__ __launch_bounds__(256) void k2_A(const short* __restrict__ eB,
                                            const short* __restrict__ WvP,
                                            const float* __restrict__ bv,
                                            short* __restrict__ AB) {
  __shared__ __align__(16) short BW[128 * 136];
  const int btile = blockIdx.x, l = blockIdx.y, tid = threadIdx.x;
  stage_bt<16, 128, 136>(BW, WvP + l * 16384, tid);
  __syncthreads();
  const int lane = tid & 63, wave = tid >> 6, lr = lane & 15, kg = lane >> 4;
  const int rowbase = btile * 64 + wave * 16;
  float bvv[8];
  #pragma unroll
  for (int m = 0; m < 8; ++m) bvv[m] = bv[l * 128 + m * 16 + lr];
  f32x4 Sacc[8];
  #pragma unroll
  for (int m = 0; m < 8; ++m) Sacc[m] = f32x4{0.f, 0.f, 0.f, 0.f};
  for (int j = 0; j < 8; ++j) {
    f32x4 acc[8];
    #pragma unroll
    for (int m = 0; m < 8; ++m) acc[m] = f32x4{0.f, 0.f, 0.f, 0.f};
    const short* ep = eB + (size_t)(j * 8192 + rowbase + lr) * 128;
    #pragma unroll
    for (int ks = 0; ks < 4; ++ks) {
      short8 a = *(const short8*)(ep + ks * 32 + kg * 8);
      #pragma unroll
      for (int m = 0; m < 8; ++m) {
        short8 b = *(const short8*)(&BW[(m * 16 + lr) * 136 + ks * 32 + kg * 8]);
        acc[m] = mfma16(a, b, acc[m]);
      }
    }
    #pragma unroll
    for (int m = 0; m < 8; ++m)
      #pragma unroll
      for (int r = 0; r < 4; ++r) {
        float x = acc[m][r] + bvv[m];
        Sacc[m][r] += (x > 0.f ? x : 0.01f * x);
      }
  }
  for (int j = 0; j < 8; ++j) {
    f32x4 acc[8];
    #pragma unroll
    for (int m = 0; m < 8; ++m) acc[m] = f32x4{0.f, 0.f, 0.f, 0.f};
    const short* ep = eB + (size_t)(j * 8192 + rowbase + lr) * 128;
    #pragma unroll
    for (int ks = 0; ks < 4; ++ks) {
      short8 a = *(const short8*)(ep + ks * 32 + kg * 8);
      #pragma unroll
      for (int m = 0; m < 8; ++m) {
        short8 b = *(const short8*)(&BW[(m * 16 + lr) * 136 + ks * 32 + kg * 8]);
        acc[m] = mfma16(a, b, acc[m]);
      }
    }
    #pragma unroll
    for (int r = 0; r < 4; ++r) {
      short8 pkt;
      #pragma unroll
      for (int m = 0; m < 8; ++m) {
        float x = acc[m][r] + bvv[m];
        x = (x > 0.f) ? x : 0.01f * x;
        pkt[m] = f2bf(Sacc[m][r] - x);
      }
      *(short8*)(AB + (size_t)(j * 8192 + rowbase + kg * 4 + r) * 1024 +
                 l * 128 + lr * 8) = pkt;
    }
  }
}

__global__ __launch_bounds__(512, 2) void k3_g(const short* __restrict__ eB,
                                               const short* __restrict__ AB,
                                               const short* __restrict__ W1P,
                                               const float* __restrict__ b1,
                                               const float* __restrict__ W2,
                                               const float* __restrict__ b2,
                                               float* __restrict__ out) {
  __shared__ __align__(16) short BW[2][128 * 128];
  const int bid = blockIdx.x;
  const int i = bid & 7;
  const int btile = bid >> 3;
  const int tid = threadIdx.x;
  const int lane = tid & 63, wave = tid >> 6, lr = lane & 15, kg = lane >> 4;
  const int lr8 = lane & 7;
  const int rowbase = btile * 128 + wave * 16;
  const short* w1 = W1P + (size_t)i * 147456;

#define STAGE_W1(buf, koff)                                                    \
  {                                                                            \
    _Pragma("unroll") for (int t = 0; t < 4; ++t) {                            \
      int G = t * 512 + tid;                                                   \
      int cG = G >> 4, gl = G & 15;                                            \
      async_copy16((buf) + (t * 512 + wave * 64) * 8,                          \
                   w1 + cG * 1152 + (koff) + ((gl ^ (cG & 7)) << 3));          \
    }                                                                          \
  }

  const short* abase = AB + (size_t)(i * 8192 + rowbase + lr) * 1024;
  const short* ebase = eB + (size_t)(i * 8192 + rowbase + lr) * 128;

  short8 ea[4], aa[4], aap[4];
  #pragma unroll
  for (int ks = 0; ks < 4; ++ks) {
    ea[ks] = *(const short8*)(ebase + (ks * 4 + kg) * 8);
    aa[ks] = *(const short8*)(abase + (ks * 4 + kg) * 8);
  }
  f32x4 hacc[8];
  #pragma unroll
  for (int m = 0; m < 8; ++m) hacc[m] = f32x4{0.f, 0.f, 0.f, 0.f};

  STAGE_W1(BW[0], 0);
  for (int c = 0; c < 9; ++c) {
    __syncthreads();
    if (c < 8) { STAGE_W1(BW[(c + 1) & 1], (c + 1 == 8) ? 1024 : (c + 1) * 128); }
    if (c + 1 < 8) {
      #pragma unroll
      for (int ks = 0; ks < 4; ++ks)
        aap[ks] = *(const short8*)(abase + (c + 1) * 128 + (ks * 4 + kg) * 8);
    }
    const short* bw = BW[c & 1];
    #pragma unroll
    for (int ks = 0; ks < 4; ++ks)
      #pragma unroll
      for (int m = 0; m < 8; ++m) {
        short8 b = *(const short8*)(bw + (m * 16 + lr) * 128 +
                                    (((ks * 4 + kg) ^ lr8) << 3));
        hacc[m] = mfma16(aa[ks], b, hacc[m]);
      }
    if (c + 1 < 8) {
      #pragma unroll
      for (int ks = 0; ks < 4; ++ks) aa[ks] = aap[ks];
    } else {
      #pragma unroll
      for (int ks = 0; ks < 4; ++ks) aa[ks] = ea[ks];
    }
  }
#undef STAGE_W1

  float sacc[4] = {0.f, 0.f, 0.f, 0.f};
  #pragma unroll
  for (int m = 0; m < 8; ++m) {
    int col = m * 16 + lr;
    float b1v = b1[i * 128 + col];
    float w2v = W2[i * 128 + col];
    #pragma unroll
    for (int r = 0; r < 4; ++r) {
      float h = hacc[m][r] + b1v;
      h = h > 0.f ? h : 0.f;
      sacc[r] += h * w2v;
    }
  }
  #pragma unroll
  for (int r = 0; r < 4; ++r) {
    float v = sacc[r];
    v += __shfl_xor(v, 1);
    v += __shfl_xor(v, 2);
    v += __shfl_xor(v, 4);
    v += __shfl_xor(v, 8);
    if (lr == 0) out[i * 8192 + rowbase + kg * 4 + r] = v + b2[i];
  }
}

extern "C" void kernel_launch(void* const* d_in, const int* in_sizes, int n_in,
                              void* d_out, int out_size, void* d_ws, size_t ws_size,
                              hipStream_t stream) {
  const float* obs = (const float*)d_in[0];
  const float* act = (const float*)d_in[1];
  const float* Wg  = (const float*)d_in[2];
  const float* bg  = (const float*)d_in[3];
  // d_in[4..7] = Wq,bq,Wk,bk: dead (softmax over singleton axis == 1)
  const float* Wv  = (const float*)d_in[8];
  const float* bv  = (const float*)d_in[9];
  const float* W1  = (const float*)d_in[10];
  const float* b1  = (const float*)d_in[11];
  const float* W2  = (const float*)d_in[12];
  const float* b2  = (const float*)d_in[13];
  float* out = (float*)d_out;

  const size_t E_N = (size_t)8 * 8192 * 128;    // eB shorts (8.4M)
  const size_t V_N = (size_t)64 * 8192 * 128;   // VBg shorts (67.1M)
  const size_t W_N = 163840 + 131072 + 1179648; // weight shorts
  const size_t NEED_FAST = (E_N + V_N + E_N + W_N) * 2;  // ~170.7 MB

  if (ws_size >= NEED_FAST) {
    short* eB  = (short*)d_ws;
    short* VBg = eB + E_N;
    short* SB  = VBg + V_N;
    short* WgT = SB + E_N;
    short* WvP = WgT + 163840;
    short* W1P = WvP + 131072;
    k0_tr<<<720, 256, 0, stream>>>(Wg, Wv, W1, WgT, WvP, W1P);
    k1_e<<<dim3(128, 8), 256, 0, stream>>>(obs, act, WgT, bg, eB);
    k2_V<<<dim3(128, 8), 256, 0, stream>>>(eB, WvP, bv, SB, VBg);
    k3_h<<<512, 512, 0, stream>>>(eB, SB, VBg, W1P, b1, W2, b2, out);
  } else {
    short* eB  = (short*)d_ws;
    short* AB  = eB + E_N;
    short* WgT = AB + V_N;
    short* WvP = WgT + 163840;
    short* W1P = WvP + 131072;
    k0_tr<<<720, 256, 0, stream>>>(Wg, Wv, W1, WgT, WvP, W1P);
    k1_e<<<dim3(128, 8), 256, 0, stream>>>(obs, act, WgT, bg, eB);
    k2_A<<<dim3(128, 8), 256, 0, stream>>>(eB, WvP, bv, AB);
    k3_g<<<512, 512, 0, stream>>>(eB, AB, W1P, b1, W2, b2, out);
  }
}

// Round 12
// 103.791 us; speedup vs baseline: 1.2402x; 1.0593x over previous
//
#include <hip/hip_runtime.h>

#define DEV static __device__ __forceinline__

typedef __attribute__((ext_vector_type(8))) short short8;
typedef __attribute__((ext_vector_type(8))) __bf16 bf16x8;
typedef __attribute__((ext_vector_type(4))) float f32x4;

// N=8 agents, B=8192, OBS=128, ACT=32, D=160, E=128, L=8
//
// pi-layout: within each 128-wide k-chunk, position p = 8*g + m holds actual
// k = 16*m + g (consistently on both MFMA operands). A lane's 8 C-layout
// accumulator values (cols 16m+lr) form one contiguous 16B granule.
//
// Register law (R5-R9): >96 simultaneous acc-live or >~120 arch-live spills.
// Work law (R10): v must be MFMA'd exactly once; S - v rides in k3's A-build.
// Cache law (R11): VBg/SB/eB (~170 MB) fit L3 -> NO nontemporal hints; NT
// stores+loads forced every v access to HBM (~900cy, 2.5 TB/s ceiling).

DEV short f2bf(float f) { return __builtin_bit_cast(short, (__bf16)f); }
DEV float bf2f(short h) {
  unsigned u = ((unsigned)(unsigned short)h) << 16;
  return __builtin_bit_cast(float, u);
}
DEV f32x4 mfma16(short8 a, short8 b, f32x4 c) {
  return __builtin_amdgcn_mfma_f32_16x16x32_bf16(
      __builtin_bit_cast(bf16x8, a), __builtin_bit_cast(bf16x8, b), c, 0, 0, 0);
}
DEV void async_copy16(short* lds, const short* g) {
  __builtin_amdgcn_global_load_lds(
      (const __attribute__((address_space(1))) void*)g,
      (__attribute__((address_space(3))) void*)lds, 16, 0, 0);
}

template <int GPC, int SRC_STRIDE, int LDS_STRIDE>
DEV void stage_bt(short* lds, const short* src, int tid) {
  constexpr int TOTAL = 128 * GPC;
  #pragma unroll
  for (int g0 = 0; g0 < TOTAL; g0 += 256) {
    int g = g0 + tid;
    int c = g / GPC, kg = g % GPC;
    *(short8*)(lds + c * LDS_STRIDE + kg * 8) =
        *(const short8*)(src + c * SRC_STRIDE + kg * 8);
  }
}

// ---- K0: weights fp32 [K][128] -> bf16 [128][K]; Wv/W1 in pi-k order -------
__global__ __launch_bounds__(256) void k0_tr(const float* __restrict__ Wg,
                                             const float* __restrict__ Wv,
                                             const float* __restrict__ W1,
                                             short* __restrict__ WgT,
                                             short* __restrict__ WvP,
                                             short* __restrict__ W1P) {
  int g = blockIdx.x * 256 + threadIdx.x;  // 184320 granules total
  short8 o;
  if (g < 20480) {  // Wg: K=160, natural k
    int n = g / 2560, rem = g % 2560;
    int c = rem & 127, kg = rem >> 7;
    const float* src = Wg + n * 20480;
    #pragma unroll
    for (int j = 0; j < 8; ++j) o[j] = f2bf(src[(size_t)(kg * 8 + j) * 128 + c]);
    *(short8*)(WgT + n * 20480 + c * 160 + kg * 8) = o;
  } else if (g < 36864) {  // Wv: K=128, pi order
    int g2 = g - 20480;
    int n = g2 >> 11, rem = g2 & 2047;
    int c = rem & 127, kg = rem >> 7;
    const float* src = Wv + n * 16384;
    #pragma unroll
    for (int j = 0; j < 8; ++j) o[j] = f2bf(src[(size_t)(16 * j + kg) * 128 + c]);
    *(short8*)(WvP + n * 16384 + c * 128 + kg * 8) = o;
  } else {  // W1: K=1152, pi order within each 128-chunk
    int g3 = g - 36864;
    int n = g3 / 18432, rem = g3 % 18432;
    int c = rem & 127, kg = rem >> 7;
    int chunk = kg >> 4, kl = kg & 15;
    const float* src = W1 + (size_t)n * 147456;
    #pragma unroll
    for (int j = 0; j < 8; ++j)
      o[j] = f2bf(src[(size_t)(chunk * 128 + 16 * j + kl) * 128 + c]);
    *(short8*)(W1P + (size_t)n * 147456 + c * 1152 + kg * 8) = o;
  }
}

// ---- K1: e = relu(oa @ Wg + bg) -> bf16, pi-packed granule stores ----------
__global__ __launch_bounds__(256) void k1_e(const float* __restrict__ obs,
                                            const float* __restrict__ act,
                                            const short* __restrict__ WgT,
                                            const float* __restrict__ bg,
                                            short* __restrict__ eB) {
  __shared__ __align__(16) short BW[128 * 168];
  const int btile = blockIdx.x, n = blockIdx.y, tid = threadIdx.x;
  stage_bt<20, 160, 168>(BW, WgT + n * 20480, tid);
  __syncthreads();
  const int lane = tid & 63, wave = tid >> 6, lr = lane & 15, kg = lane >> 4;
  const int rowbase = btile * 64 + wave * 16;
  f32x4 acc[8];
  #pragma unroll
  for (int m = 0; m < 8; ++m) acc[m] = f32x4{0.f, 0.f, 0.f, 0.f};
  const float* obsp = obs + (size_t)(n * 8192 + rowbase + lr) * 128;
  const float* actp = act + (size_t)(n * 8192 + rowbase + lr) * 32;
  #pragma unroll
  for (int ks = 0; ks < 5; ++ks) {
    const float* ap = (ks < 4) ? (obsp + ks * 32 + kg * 8) : (actp + kg * 8);
    float4 p0 = *(const float4*)ap;
    float4 p1 = *(const float4*)(ap + 4);
    short8 a;
    a[0] = f2bf(p0.x); a[1] = f2bf(p0.y); a[2] = f2bf(p0.z); a[3] = f2bf(p0.w);
    a[4] = f2bf(p1.x); a[5] = f2bf(p1.y); a[6] = f2bf(p1.z); a[7] = f2bf(p1.w);
    #pragma unroll
    for (int m = 0; m < 8; ++m) {
      short8 b = *(const short8*)(&BW[(m * 16 + lr) * 168 + ks * 32 + kg * 8]);
      acc[m] = mfma16(a, b, acc[m]);
    }
  }
  float bgv[8];
  #pragma unroll
  for (int m = 0; m < 8; ++m) bgv[m] = bg[n * 128 + m * 16 + lr];
  #pragma unroll
  for (int r = 0; r < 4; ++r) {
    short8 pkt;
    #pragma unroll
    for (int m = 0; m < 8; ++m) {
      float x = acc[m][r] + bgv[m];
      pkt[m] = f2bf(x > 0.f ? x : 0.f);
    }
    *(short8*)(eB + (size_t)(n * 8192 + rowbase + kg * 4 + r) * 128 + lr * 8) = pkt;
  }
}

// ============== FAST PATH (ws >= 171 MB): v stored once ====================
// K2V: per (btile,l): v_j = leaky(e_j@Wv_l+bv_l) -> VBg[(j*8+l)] (regular
//      stores -> L3-resident), S = sum_j v_j in regs -> SB[l].
__global__ __launch_bounds__(256) void k2_V(const short* __restrict__ eB,
                                            const short* __restrict__ WvP,
                                            const float* __restrict__ bv,
                                            short* __restrict__ SB,
                                            short* __restrict__ VBg) {
  __shared__ __align__(16) short BW[128 * 136];
  const int btile = blockIdx.x, l = blockIdx.y, tid = threadIdx.x;
  stage_bt<16, 128, 136>(BW, WvP + l * 16384, tid);
  __syncthreads();
  const int lane = tid & 63, wave = tid >> 6, lr = lane & 15, kg = lane >> 4;
  const int rowbase = btile * 64 + wave * 16;
  float bvv[8];
  #pragma unroll
  for (int m = 0; m < 8; ++m) bvv[m] = bv[l * 128 + m * 16 + lr];
  f32x4 Sacc[8];
  #pragma unroll
  for (int m = 0; m < 8; ++m) Sacc[m] = f32x4{0.f, 0.f, 0.f, 0.f};
  for (int j = 0; j < 8; ++j) {
    f32x4 acc[8];
    #pragma unroll
    for (int m = 0; m < 8; ++m) acc[m] = f32x4{0.f, 0.f, 0.f, 0.f};
    const short* ep = eB + (size_t)(j * 8192 + rowbase + lr) * 128;
    #pragma unroll
    for (int ks = 0; ks < 4; ++ks) {
      short8 a = *(const short8*)(ep + ks * 32 + kg * 8);
      #pragma unroll
      for (int m = 0; m < 8; ++m) {
        short8 b = *(const short8*)(&BW[(m * 16 + lr) * 136 + ks * 32 + kg * 8]);
        acc[m] = mfma16(a, b, acc[m]);
      }
    }
    #pragma unroll
    for (int r = 0; r < 4; ++r) {
      short8 pkt;
      #pragma unroll
      for (int m = 0; m < 8; ++m) {
        float x = acc[m][r] + bvv[m];
        x = (x > 0.f) ? x : 0.01f * x;  // leaky_relu
        Sacc[m][r] += x;
        pkt[m] = f2bf(x);
      }
      *(short8*)(VBg + (size_t)((j * 8 + l) * 8192 + rowbase + kg * 4 + r) * 128 +
                 lr * 8) = pkt;
    }
  }
  #pragma unroll
  for (int r = 0; r < 4; ++r) {
    short8 pkt;
    #pragma unroll
    for (int m = 0; m < 8; ++m) pkt[m] = f2bf(Sacc[m][r]);
    *(short8*)(SB + (size_t)(l * 8192 + rowbase + kg * 4 + r) * 128 + lr * 8) = pkt;
  }
}

// K3H: per agent, streaming GEMM. Chunk l: A-frag = bf16(S_l) - bf16(v_{l,i})
//      from prefetched sv/vv (both L3-resident); chunk 8: e@W1e.
__global__ __launch_bounds__(512, 2) void k3_h(const short* __restrict__ eB,
                                               const short* __restrict__ SB,
                                               const short* __restrict__ VBg,
                                               const short* __restrict__ W1P,
                                               const float* __restrict__ b1,
                                               const float* __restrict__ W2,
                                               const float* __restrict__ b2,
                                               float* __restrict__ out) {
  __shared__ __align__(16) short BW[2][128 * 128];  // 64 KB dbuf -> 2 blk/CU
  const int bid = blockIdx.x;
  const int i = bid & 7;        // agent -> XCD pinning
  const int btile = bid >> 3;   // 64 btiles x 128 rows
  const int tid = threadIdx.x;
  const int lane = tid & 63, wave = tid >> 6, lr = lane & 15, kg = lane >> 4;
  const int lr8 = lane & 7;
  const int rowbase = btile * 128 + wave * 16;
  const short* w1 = W1P + (size_t)i * 147456;

#define STAGE_W1(buf, koff)                                                    \
  {                                                                            \
    _Pragma("unroll") for (int t = 0; t < 4; ++t) {                            \
      int G = t * 512 + tid;                                                   \
      int cG = G >> 4, gl = G & 15;                                            \
      async_copy16((buf) + (t * 512 + wave * 64) * 8,                          \
                   w1 + cG * 1152 + (koff) + ((gl ^ (cG & 7)) << 3));          \
    }                                                                          \
  }

  const short* sbase = SB + (size_t)(rowbase + lr) * 128;          // +l*8192*128
  const short* vbase = VBg + (size_t)((i * 8) * 8192 + rowbase + lr) * 128;

  short8 sv[4], vv[4];
  #pragma unroll
  for (int ks = 0; ks < 4; ++ks) {  // prefetch chunk 0 operands
    sv[ks] = *(const short8*)(sbase + (ks * 4 + kg) * 8);
    vv[ks] = *(const short8*)(vbase + (ks * 4 + kg) * 8);
  }
  f32x4 hacc[8];
  #pragma unroll
  for (int m = 0; m < 8; ++m) hacc[m] = f32x4{0.f, 0.f, 0.f, 0.f};

  STAGE_W1(BW[0], 0);
  for (int c = 0; c < 9; ++c) {
    __syncthreads();  // stage(c) drained; BW[(c+1)&1] free
    if (c < 8) { STAGE_W1(BW[(c + 1) & 1], (c + 1 == 8) ? 1024 : (c + 1) * 128); }
    short8 aa[4];
    if (c < 8) {
      #pragma unroll
      for (int ks = 0; ks < 4; ++ks)
        #pragma unroll
        for (int jj = 0; jj < 8; ++jj)
          aa[ks][jj] = f2bf(bf2f(sv[ks][jj]) - bf2f(vv[ks][jj]));
      if (c + 1 < 8) {  // prefetch next chunk's S and v fragments
        #pragma unroll
        for (int ks = 0; ks < 4; ++ks) {
          sv[ks] = *(const short8*)(sbase + (size_t)(c + 1) * 8192 * 128 +
                                    (ks * 4 + kg) * 8);
          vv[ks] = *(const short8*)(vbase + (size_t)(c + 1) * 8192 * 128 +
                                    (ks * 4 + kg) * 8);
        }
      } else {  // load e-frags into sv for the final chunk
        #pragma unroll
        for (int ks = 0; ks < 4; ++ks)
          sv[ks] = *(const short8*)(
              eB + (size_t)(i * 8192 + rowbase + lr) * 128 + (ks * 4 + kg) * 8);
      }
    } else {
      #pragma unroll
      for (int ks = 0; ks < 4; ++ks) aa[ks] = sv[ks];  // e fragments
    }
    const short* bw = BW[c & 1];
    #pragma unroll
    for (int ks = 0; ks < 4; ++ks)
      #pragma unroll
      for (int m = 0; m < 8; ++m) {
        short8 b = *(const short8*)(bw + (m * 16 + lr) * 128 +
                                    (((ks * 4 + kg) ^ lr8) << 3));
        hacc[m] = mfma16(aa[ks], b, hacc[m]);
      }
  }
#undef STAGE_W1

  // epilogue: h = relu(hacc + b1); out = h . W2 + b2
  float sacc[4] = {0.f, 0.f, 0.f, 0.f};
  #pragma unroll
  for (int m = 0; m < 8; ++m) {
    int col = m * 16 + lr;
    float b1v = b1[i * 128 + col];
    float w2v = W2[i * 128 + col];
    #pragma unroll
    for (int r = 0; r < 4; ++r) {
      float h = hacc[m][r] + b1v;
      h = h > 0.f ? h : 0.f;
      sacc[r] += h * w2v;
    }
  }
  #pragma unroll
  for (int r = 0; r < 4; ++r) {
    float v = sacc[r];
    v += __shfl_xor(v, 1);
    v += __shfl_xor(v, 2);
    v += __shfl_xor(v, 4);
    v += __shfl_xor(v, 8);
    if (lr == 0) out[i * 8192 + rowbase + kg * 4 + r] = v + b2[i];
  }
}

// ============== FALLBACK PATH (ws < 171 MB): R10 structure =================
__global__ __launch_bounds__(256) void k2_A(const short* __restrict__ eB,
                                            const short* __restrict__ WvP,
                                            const float* __restrict__ bv,
                                            short* __restrict__ AB) {
  __shared__ __align__(16) short BW[128 * 136];
  const int btile = blockIdx.x, l = blockIdx.y, tid = threadIdx.x;
  stage_bt<16, 128, 136>(BW, WvP + l * 16384, tid);
  __syncthreads();
  const int lane = tid & 63, wave = tid >> 6, lr = lane & 15, kg = lane >> 4;
  const int rowbase = btile * 64 + wave * 16;
  float bvv[8];
  #pragma unroll
  for (int m = 0; m < 8; ++m) bvv[m] = bv[l * 128 + m * 16 + lr];
  f32x4 Sacc[8];
  #pragma unroll
  for (int m = 0; m < 8; ++m) Sacc[m] = f32x4{0.f, 0.f, 0.f, 0.f};
  for (int j = 0; j < 8; ++j) {
    f32x4 acc[8];
    #pragma unroll
    for (int m = 0; m < 8; ++m) acc[m] = f32x4{0.f, 0.f, 0.f, 0.f};
    const short* ep = eB + (size_t)(j * 8192 + rowbase + lr) * 128;
    #pragma unroll
    for (int ks = 0; ks < 4; ++ks) {
      short8 a = *(const short8*)(ep + ks * 32 + kg * 8);
      #pragma unroll
      for (int m = 0; m < 8; ++m) {
        short8 b = *(const short8*)(&BW[(m * 16 + lr) * 136 + ks * 32 + kg * 8]);
        acc[m] = mfma16(a, b, acc[m]);
      }
    }
    #pragma unroll
    for (int m = 0; m < 8; ++m)
      #pragma unroll
      for (int r = 0; r < 4; ++r) {
        float x = acc[m][r] + bvv[m];
        Sacc[m][r] += (x > 0.f ? x : 0.01f * x);
      }
  }
  for (int j = 0; j < 8; ++j) {
    f32x4 acc[8];
    #pragma unroll
    for (int m = 0; m < 8; ++m) acc[m] = f32x4{0.f, 0.f, 0.f, 0.f};
    const short* ep = eB + (size_t)(j * 8192 + rowbase + lr) * 128;
    #pragma unroll
    for (int ks = 0; ks < 4; ++ks) {
      short8 a = *(const short8*)(ep + ks * 32 + kg * 8);
      #pragma unroll
      for (int m = 0; m < 8; ++m) {
        short8 b = *(const short8*)(&BW[(m * 16 + lr) * 136 + ks * 32 + kg * 8]);
        acc[m] = mfma16(a, b, acc[m]);
      }
    }
    #pragma unroll
    for (int r = 0; r < 4; ++r) {
      short8 pkt;
      #pragma unroll
      for (int m = 0; m < 8; ++m) {
        float x = acc[m][r] + bvv[m];
        x = (x > 0.f) ? x : 0.01f * x;
        pkt[m] = f2bf(Sacc[m][r] - x);
      }
      *(short8*)(AB + (size_t)(j * 8192 + rowbase + kg * 4 + r) * 1024 +
                 l * 128 + lr * 8) = pkt;
    }
  }
}

__global__ __launch_bounds__(512, 2) void k3_g(const short* __restrict__ eB,
                                               const short* __restrict__ AB,
                                               const short* __restrict__ W1P,
                                               const float* __restrict__ b1,
                                               const float* __restrict__ W2,
                                               const float* __restrict__ b2,
                                               float* __restrict__ out) {
  __shared__ __align__(16) short BW[2][128 * 128];
  const int bid = blockIdx.x;
  const int i = bid & 7;
  const int btile = bid >> 3;
  const int tid = threadIdx.x;
  const int lane = tid & 63, wave = tid >> 6, lr = lane & 15, kg = lane >> 4;
  const int lr8 = lane & 7;
  const int rowbase = btile * 128 + wave * 16;
  const short* w1 = W1P + (size_t)i * 147456;

#define STAGE_W1(buf, koff)                                                    \
  {                                                                            \
    _Pragma("unroll") for (int t = 0; t < 4; ++t) {                            \
      int G = t * 512 + tid;                                                   \
      int cG = G >> 4, gl = G & 15;                                            \
      async_copy16((buf) + (t * 512 + wave * 64) * 8,                          \
                   w1 + cG * 1152 + (koff) + ((gl ^ (cG & 7)) << 3));          \
    }                                                                          \
  }

  const short* abase = AB + (size_t)(i * 8192 + rowbase + lr) * 1024;
  const short* ebase = eB + (size_t)(i * 8192 + rowbase + lr) * 128;

  short8 ea[4], aa[4], aap[4];
  #pragma unroll
  for (int ks = 0; ks < 4; ++ks) {
    ea[ks] = *(const short8*)(ebase + (ks * 4 + kg) * 8);
    aa[ks] = *(const short8*)(abase + (ks * 4 + kg) * 8);
  }
  f32x4 hacc[8];
  #pragma unroll
  for (int m = 0; m < 8; ++m) hacc[m] = f32x4{0.f, 0.f, 0.f, 0.f};

  STAGE_W1(BW[0], 0);
  for (int c = 0; c < 9; ++c) {
    __syncthreads();
    if (c < 8) { STAGE_W1(BW[(c + 1) & 1], (c + 1 == 8) ? 1024 : (c + 1) * 128); }
    if (c + 1 < 8) {
      #pragma unroll
      for (int ks = 0; ks < 4; ++ks)
        aap[ks] = *(const short8*)(abase + (c + 1) * 128 + (ks * 4 + kg) * 8);
    }
    const short* bw = BW[c & 1];
    #pragma unroll
    for (int ks = 0; ks < 4; ++ks)
      #pragma unroll
      for (int m = 0; m < 8; ++m) {
        short8 b = *(const short8*)(bw + (m * 16 + lr) * 128 +
                                    (((ks * 4 + kg) ^ lr8) << 3));
        hacc[m] = mfma16(aa[ks], b, hacc[m]);
      }
    if (c + 1 < 8) {
      #pragma unroll
      for (int ks = 0; ks < 4; ++ks) aa[ks] = aap[ks];
    } else {
      #pragma unroll
      for (int ks = 0; ks < 4; ++ks) aa[ks] = ea[ks];
    }
  }
#undef STAGE_W1

  float sacc[4] = {0.f, 0.f, 0.f, 0.f};
  #pragma unroll
  for (int m = 0; m < 8; ++m) {
    int col = m * 16 + lr;
    float b1v = b1[i * 128 + col];
    float w2v = W2[i * 128 + col];
    #pragma unroll
    for (int r = 0; r < 4; ++r) {
      float h = hacc[m][r] + b1v;
      h = h > 0.f ? h : 0.f;
      sacc[r] += h * w2v;
    }
  }
  #pragma unroll
  for (int r = 0; r < 4; ++r) {
    float v = sacc[r];
    v += __shfl_xor(v, 1);
    v += __shfl_xor(v, 2);
    v += __shfl_xor(v, 4);
    v += __shfl_xor(v, 8);
    if (lr == 0) out[i * 8192 + rowbase + kg * 4 + r] = v + b2[i];
  }
}

extern "C" void kernel_launch(void* const* d_in, const int* in_sizes, int n_in,
                              void* d_out, int out_size, void* d_ws, size_t ws_size,
                              hipStream_t stream) {
  const float* obs = (const float*)d_in[0];
  const float* act = (const float*)d_in[1];
  const float* Wg  = (const float*)d_in[2];
  const float* bg  = (const float*)d_in[3];
  // d_in[4..7] = Wq,bq,Wk,bk: dead (softmax over singleton axis == 1)
  const float* Wv  = (const float*)d_in[8];
  const float* bv  = (const float*)d_in[9];
  const float* W1  = (const float*)d_in[10];
  const float* b1  = (const float*)d_in[11];
  const float* W2  = (const float*)d_in[12];
  const float* b2  = (const float*)d_in[13];
  float* out = (float*)d_out;

  const size_t E_N = (size_t)8 * 8192 * 128;    // eB shorts (8.4M)
  const size_t V_N = (size_t)64 * 8192 * 128;   // VBg shorts (67.1M)
  const size_t W_N = 163840 + 131072 + 1179648; // weight shorts
  const size_t NEED_FAST = (E_N + V_N + E_N + W_N) * 2;  // ~170.7 MB

  if (ws_size >= NEED_FAST) {
    short* eB  = (short*)d_ws;
    short* VBg = eB + E_N;
    short* SB  = VBg + V_N;
    short* WgT = SB + E_N;
    short* WvP = WgT + 163840;
    short* W1P = WvP + 131072;
    k0_tr<<<720, 256, 0, stream>>>(Wg, Wv, W1, WgT, WvP, W1P);
    k1_e<<<dim3(128, 8), 256, 0, stream>>>(obs, act, WgT, bg, eB);
    k2_V<<<dim3(128, 8), 256, 0, stream>>>(eB, WvP, bv, SB, VBg);
    k3_h<<<512, 512, 0, stream>>>(eB, SB, VBg, W1P, b1, W2, b2, out);
  } else {
    short* eB  = (short*)d_ws;
    short* AB  = eB + E_N;
    short* WgT = AB + V_N;
    short* WvP = WgT + 163840;
    short* W1P = WvP + 131072;
    k0_tr<<<720, 256, 0, stream>>>(Wg, Wv, W1, WgT, WvP, W1P);
    k1_e<<<dim3(128, 8), 256, 0, stream>>>(obs, act, WgT, bg, eB);
    k2_A<<<dim3(128, 8), 256, 0, stream>>>(eB, WvP, bv, AB);
    k3_g<<<512, 512, 0, stream>>>(eB, AB, W1P, b1, W2, b2, out);
  }
}

// Round 13
// 98.076 us; speedup vs baseline: 1.3124x; 1.0583x over previous
//
#include <hip/hip_runtime.h>

#define DEV static __device__ __forceinline__

typedef __attribute__((ext_vector_type(8))) short short8;
typedef __attribute__((ext_vector_type(8))) __bf16 bf16x8;
typedef __attribute__((ext_vector_type(4))) float f32x4;
typedef __attribute__((ext_vector_type(2))) float f32x2;

// N=8 agents, B=8192, OBS=128, ACT=32, D=160, E=128, L=8
//
// pi-layout: within each 128-wide k-chunk, position p = 8*g + m holds actual
// k = 16*m + g (consistently on both MFMA operands). A lane's 8 C-layout
// accumulator values (cols 16m+lr) form one contiguous granule.
//
// Register law (R5-R9): >96 simultaneous acc-live or >~120 arch-live spills.
// Work law (R10): v is MFMA'd exactly once; S - v rides in k3's A-build.
// Cache law (R11): workspace tensors are L3-candidates -> no NT hints.
// Byte law (R12): k2_V/k3_h run at the memory-system per-CU ceiling
// (~11 B/cy/CU) -> only byte reduction helps. Hence v stored as FP8 e4m3
// (S stays f32-accumulated; only the subtrahend is quantized).

DEV short f2bf(float f) { return __builtin_bit_cast(short, (__bf16)f); }
DEV float bf2f(short h) {
  unsigned u = ((unsigned)(unsigned short)h) << 16;
  return __builtin_bit_cast(float, u);
}
DEV f32x4 mfma16(short8 a, short8 b, f32x4 c) {
  return __builtin_amdgcn_mfma_f32_16x16x32_bf16(
      __builtin_bit_cast(bf16x8, a), __builtin_bit_cast(bf16x8, b), c, 0, 0, 0);
}
DEV void async_copy16(short* lds, const short* g) {
  __builtin_amdgcn_global_load_lds(
      (const __attribute__((address_space(1))) void*)g,
      (__attribute__((address_space(3))) void*)lds, 16, 0, 0);
}

template <int GPC, int SRC_STRIDE, int LDS_STRIDE>
DEV void stage_bt(short* lds, const short* src, int tid) {
  constexpr int TOTAL = 128 * GPC;
  #pragma unroll
  for (int g0 = 0; g0 < TOTAL; g0 += 256) {
    int g = g0 + tid;
    int c = g / GPC, kg = g % GPC;
    *(short8*)(lds + c * LDS_STRIDE + kg * 8) =
        *(const short8*)(src + c * SRC_STRIDE + kg * 8);
  }
}

// ---- K0: weights fp32 [K][128] -> bf16 [128][K]; Wv/W1 in pi-k order -------
__global__ __launch_bounds__(256) void k0_tr(const float* __restrict__ Wg,
                                             const float* __restrict__ Wv,
                                             const float* __restrict__ W1,
                                             short* __restrict__ WgT,
                                             short* __restrict__ WvP,
                                             short* __restrict__ W1P) {
  int g = blockIdx.x * 256 + threadIdx.x;  // 184320 granules total
  short8 o;
  if (g < 20480) {  // Wg: K=160, natural k
    int n = g / 2560, rem = g % 2560;
    int c = rem & 127, kg = rem >> 7;
    const float* src = Wg + n * 20480;
    #pragma unroll
    for (int j = 0; j < 8; ++j) o[j] = f2bf(src[(size_t)(kg * 8 + j) * 128 + c]);
    *(short8*)(WgT + n * 20480 + c * 160 + kg * 8) = o;
  } else if (g < 36864) {  // Wv: K=128, pi order
    int g2 = g - 20480;
    int n = g2 >> 11, rem = g2 & 2047;
    int c = rem & 127, kg = rem >> 7;
    const float* src = Wv + n * 16384;
    #pragma unroll
    for (int j = 0; j < 8; ++j) o[j] = f2bf(src[(size_t)(16 * j + kg) * 128 + c]);
    *(short8*)(WvP + n * 16384 + c * 128 + kg * 8) = o;
  } else {  // W1: K=1152, pi order within each 128-chunk
    int g3 = g - 36864;
    int n = g3 / 18432, rem = g3 % 18432;
    int c = rem & 127, kg = rem >> 7;
    int chunk = kg >> 4, kl = kg & 15;
    const float* src = W1 + (size_t)n * 147456;
    #pragma unroll
    for (int j = 0; j < 8; ++j)
      o[j] = f2bf(src[(size_t)(chunk * 128 + 16 * j + kl) * 128 + c]);
    *(short8*)(W1P + (size_t)n * 147456 + c * 1152 + kg * 8) = o;
  }
}

// ---- K1: e = relu(oa @ Wg + bg) -> bf16, pi-packed granule stores ----------
__global__ __launch_bounds__(256) void k1_e(const float* __restrict__ obs,
                                            const float* __restrict__ act,
                                            const short* __restrict__ WgT,
                                            const float* __restrict__ bg,
                                            short* __restrict__ eB) {
  __shared__ __align__(16) short BW[128 * 168];
  const int btile = blockIdx.x, n = blockIdx.y, tid = threadIdx.x;
  stage_bt<20, 160, 168>(BW, WgT + n * 20480, tid);
  __syncthreads();
  const int lane = tid & 63, wave = tid >> 6, lr = lane & 15, kg = lane >> 4;
  const int rowbase = btile * 64 + wave * 16;
  f32x4 acc[8];
  #pragma unroll
  for (int m = 0; m < 8; ++m) acc[m] = f32x4{0.f, 0.f, 0.f, 0.f};
  const float* obsp = obs + (size_t)(n * 8192 + rowbase + lr) * 128;
  const float* actp = act + (size_t)(n * 8192 + rowbase + lr) * 32;
  #pragma unroll
  for (int ks = 0; ks < 5; ++ks) {
    const float* ap = (ks < 4) ? (obsp + ks * 32 + kg * 8) : (actp + kg * 8);
    float4 p0 = *(const float4*)ap;
    float4 p1 = *(const float4*)(ap + 4);
    short8 a;
    a[0] = f2bf(p0.x); a[1] = f2bf(p0.y); a[2] = f2bf(p0.z); a[3] = f2bf(p0.w);
    a[4] = f2bf(p1.x); a[5] = f2bf(p1.y); a[6] = f2bf(p1.z); a[7] = f2bf(p1.w);
    #pragma unroll
    for (int m = 0; m < 8; ++m) {
      short8 b = *(const short8*)(&BW[(m * 16 + lr) * 168 + ks * 32 + kg * 8]);
      acc[m] = mfma16(a, b, acc[m]);
    }
  }
  float bgv[8];
  #pragma unroll
  for (int m = 0; m < 8; ++m) bgv[m] = bg[n * 128 + m * 16 + lr];
  #pragma unroll
  for (int r = 0; r < 4; ++r) {
    short8 pkt;
    #pragma unroll
    for (int m = 0; m < 8; ++m) {
      float x = acc[m][r] + bgv[m];
      pkt[m] = f2bf(x > 0.f ? x : 0.f);
    }
    *(short8*)(eB + (size_t)(n * 8192 + rowbase + kg * 4 + r) * 128 + lr * 8) = pkt;
  }
}

// ============== FAST PATH: v stored once, FP8 e4m3 =========================
// K2V: per (btile,l): v_j = leaky(e_j@Wv_l+bv_l) -> VBg[(j*8+l)] (fp8, 8B
//      granule stores), S = sum_j v_j in f32 regs -> SB[l] (bf16).
__global__ __launch_bounds__(256) void k2_V(const short* __restrict__ eB,
                                            const short* __restrict__ WvP,
                                            const float* __restrict__ bv,
                                            short* __restrict__ SB,
                                            unsigned char* __restrict__ VBg) {
  __shared__ __align__(16) short BW[128 * 136];
  const int btile = blockIdx.x, l = blockIdx.y, tid = threadIdx.x;
  stage_bt<16, 128, 136>(BW, WvP + l * 16384, tid);
  __syncthreads();
  const int lane = tid & 63, wave = tid >> 6, lr = lane & 15, kg = lane >> 4;
  const int rowbase = btile * 64 + wave * 16;
  float bvv[8];
  #pragma unroll
  for (int m = 0; m < 8; ++m) bvv[m] = bv[l * 128 + m * 16 + lr];
  f32x4 Sacc[8];
  #pragma unroll
  for (int m = 0; m < 8; ++m) Sacc[m] = f32x4{0.f, 0.f, 0.f, 0.f};
  for (int j = 0; j < 8; ++j) {
    f32x4 acc[8];
    #pragma unroll
    for (int m = 0; m < 8; ++m) acc[m] = f32x4{0.f, 0.f, 0.f, 0.f};
    const short* ep = eB + (size_t)(j * 8192 + rowbase + lr) * 128;
    #pragma unroll
    for (int ks = 0; ks < 4; ++ks) {
      short8 a = *(const short8*)(ep + ks * 32 + kg * 8);
      #pragma unroll
      for (int m = 0; m < 8; ++m) {
        short8 b = *(const short8*)(&BW[(m * 16 + lr) * 136 + ks * 32 + kg * 8]);
        acc[m] = mfma16(a, b, acc[m]);
      }
    }
    #pragma unroll
    for (int r = 0; r < 4; ++r) {
      float x[8];
      #pragma unroll
      for (int m = 0; m < 8; ++m) {
        float t = acc[m][r] + bvv[m];
        t = (t > 0.f) ? t : 0.01f * t;  // leaky_relu
        Sacc[m][r] += t;
        x[m] = t;
      }
      unsigned lo = 0, hi = 0;
      lo = __builtin_amdgcn_cvt_pk_fp8_f32(x[0], x[1], lo, false);
      lo = __builtin_amdgcn_cvt_pk_fp8_f32(x[2], x[3], lo, true);
      hi = __builtin_amdgcn_cvt_pk_fp8_f32(x[4], x[5], hi, false);
      hi = __builtin_amdgcn_cvt_pk_fp8_f32(x[6], x[7], hi, true);
      uint2 o{lo, hi};
      *(uint2*)(VBg + (size_t)((j * 8 + l) * 8192 + rowbase + kg * 4 + r) * 128 +
                lr * 8) = o;
    }
  }
  #pragma unroll
  for (int r = 0; r < 4; ++r) {
    short8 pkt;
    #pragma unroll
    for (int m = 0; m < 8; ++m) pkt[m] = f2bf(Sacc[m][r]);
    *(short8*)(SB + (size_t)(l * 8192 + rowbase + kg * 4 + r) * 128 + lr * 8) = pkt;
  }
}

// K3H: per agent, streaming GEMM. Chunk l: A-frag = bf16(S_l) - fp8(v_{l,i})
//      from prefetched sv (bf16 b128) + vv (fp8 8B); chunk 8: e@W1e.
__global__ __launch_bounds__(512, 2) void k3_h(const short* __restrict__ eB,
                                               const short* __restrict__ SB,
                                               const unsigned char* __restrict__ VBg,
                                               const short* __restrict__ W1P,
                                               const float* __restrict__ b1,
                                               const float* __restrict__ W2,
                                               const float* __restrict__ b2,
                                               float* __restrict__ out) {
  __shared__ __align__(16) short BW[2][128 * 128];  // 64 KB dbuf -> 2 blk/CU
  const int bid = blockIdx.x;
  const int i = bid & 7;        // agent -> XCD pinning
  const int btile = bid >> 3;   // 64 btiles x 128 rows
  const int tid = threadIdx.x;
  const int lane = tid & 63, wave = tid >> 6, lr = lane & 15, kg = lane >> 4;
  const int lr8 = lane & 7;
  const int rowbase = btile * 128 + wave * 16;
  const short* w1 = W1P + (size_t)i * 147456;

#define STAGE_W1(buf, koff)                                                    \
  {                                                                            \
    _Pragma("unroll") for (int t = 0; t < 4; ++t) {                            \
      int G = t * 512 + tid;                                                   \
      int cG = G >> 4, gl = G & 15;                                            \
      async_copy16((buf) + (t * 512 + wave * 64) * 8,                          \
                   w1 + cG * 1152 + (koff) + ((gl ^ (cG & 7)) << 3));          \
    }                                                                          \
  }

  const short* sbase = SB + (size_t)(rowbase + lr) * 128;  // + l*8192*128
  const unsigned char* vbase =
      VBg + (size_t)((i * 8) * 8192 + rowbase + lr) * 128;  // + l*8192*128

  short8 sv[4];
  uint2 vv[4];
  #pragma unroll
  for (int ks = 0; ks < 4; ++ks) {  // prefetch chunk 0 operands
    sv[ks] = *(const short8*)(sbase + (ks * 4 + kg) * 8);
    vv[ks] = *(const uint2*)(vbase + (ks * 4 + kg) * 8);
  }
  f32x4 hacc[8];
  #pragma unroll
  for (int m = 0; m < 8; ++m) hacc[m] = f32x4{0.f, 0.f, 0.f, 0.f};

  STAGE_W1(BW[0], 0);
  for (int c = 0; c < 9; ++c) {
    __syncthreads();  // stage(c) drained; BW[(c+1)&1] free
    if (c < 8) { STAGE_W1(BW[(c + 1) & 1], (c + 1 == 8) ? 1024 : (c + 1) * 128); }
    short8 aa[4];
    if (c < 8) {
      #pragma unroll
      for (int ks = 0; ks < 4; ++ks) {
        f32x2 f01 = __builtin_amdgcn_cvt_pk_f32_fp8((int)vv[ks].x, false);
        f32x2 f23 = __builtin_amdgcn_cvt_pk_f32_fp8((int)vv[ks].x, true);
        f32x2 f45 = __builtin_amdgcn_cvt_pk_f32_fp8((int)vv[ks].y, false);
        f32x2 f67 = __builtin_amdgcn_cvt_pk_f32_fp8((int)vv[ks].y, true);
        aa[ks][0] = f2bf(bf2f(sv[ks][0]) - f01.x);
        aa[ks][1] = f2bf(bf2f(sv[ks][1]) - f01.y);
        aa[ks][2] = f2bf(bf2f(sv[ks][2]) - f23.x);
        aa[ks][3] = f2bf(bf2f(sv[ks][3]) - f23.y);
        aa[ks][4] = f2bf(bf2f(sv[ks][4]) - f45.x);
        aa[ks][5] = f2bf(bf2f(sv[ks][5]) - f45.y);
        aa[ks][6] = f2bf(bf2f(sv[ks][6]) - f67.x);
        aa[ks][7] = f2bf(bf2f(sv[ks][7]) - f67.y);
      }
      if (c + 1 < 8) {  // prefetch next chunk's S and v fragments
        #pragma unroll
        for (int ks = 0; ks < 4; ++ks) {
          sv[ks] = *(const short8*)(sbase + (size_t)(c + 1) * 8192 * 128 +
                                    (ks * 4 + kg) * 8);
          vv[ks] = *(const uint2*)(vbase + (size_t)(c + 1) * 8192 * 128 +
                                   (ks * 4 + kg) * 8);
        }
      } else {  // load e-frags into sv for the final chunk
        #pragma unroll
        for (int ks = 0; ks < 4; ++ks)
          sv[ks] = *(const short8*)(
              eB + (size_t)(i * 8192 + rowbase + lr) * 128 + (ks * 4 + kg) * 8);
      }
    } else {
      #pragma unroll
      for (int ks = 0; ks < 4; ++ks) aa[ks] = sv[ks];  // e fragments
    }
    const short* bw = BW[c & 1];
    #pragma unroll
    for (int ks = 0; ks < 4; ++ks)
      #pragma unroll
      for (int m = 0; m < 8; ++m) {
        short8 b = *(const short8*)(bw + (m * 16 + lr) * 128 +
                                    (((ks * 4 + kg) ^ lr8) << 3));
        hacc[m] = mfma16(aa[ks], b, hacc[m]);
      }
  }
#undef STAGE_W1

  // epilogue: h = relu(hacc + b1); out = h . W2 + b2
  float sacc[4] = {0.f, 0.f, 0.f, 0.f};
  #pragma unroll
  for (int m = 0; m < 8; ++m) {
    int col = m * 16 + lr;
    float b1v = b1[i * 128 + col];
    float w2v = W2[i * 128 + col];
    #pragma unroll
    for (int r = 0; r < 4; ++r) {
      float h = hacc[m][r] + b1v;
      h = h > 0.f ? h : 0.f;
      sacc[r] += h * w2v;
    }
  }
  #pragma unroll
  for (int r = 0; r < 4; ++r) {
    float v = sacc[r];
    v += __shfl_xor(v, 1);
    v += __shfl_xor(v, 2);
    v += __shfl_xor(v, 4);
    v += __shfl_xor(v, 8);
    if (lr == 0) out[i * 8192 + rowbase + kg * 4 + r] = v + b2[i];
  }
}

// ============== FALLBACK PATH (small ws): R10 structure ====================
__global__ __launch_bounds__(256) void k2_A(const short* __restrict__ eB,
                                            const short* __restrict__ WvP,
                                            const float* __restrict__ bv,
                                            short* __restrict__ AB) {
  __shared__ __align__(16) short BW[128 * 136];
  const int btile = blockIdx.x, l = blockIdx.y, tid = threadIdx.x;
  stage_bt<16, 128, 136>(BW, WvP + l * 16384, tid);
  __syncthreads();
  const int lane = tid & 63, wave = tid >> 6, lr = lane & 15, kg = lane >> 4;
  const int rowbase = btile * 64 + wave * 16;
  float bvv[8];
  #pragma unroll
  for (int m = 0; m < 8; ++m) bvv[m] = bv[l * 128 + m * 16 + lr];
  f32x4 Sacc[8];
  #pragma unroll
  for (int m = 0; m < 8; ++m) Sacc[m] = f32x4{0.f, 0.f, 0.f, 0.f};
  for (int j = 0; j < 8; ++j) {
    f32x4 acc[8];
    #pragma unroll
    for (int m = 0; m < 8; ++m) acc[m] = f32x4{0.f, 0.f, 0.f, 0.f};
    const short* ep = eB + (size_t)(j * 8192 + rowbase + lr) * 128;
    #pragma unroll
    for (int ks = 0; ks < 4; ++ks) {
      short8 a = *(const short8*)(ep + ks * 32 + kg * 8);
      #pragma unroll
      for (int m = 0; m < 8; ++m) {
        short8 b = *(const short8*)(&BW[(m * 16 + lr) * 136 + ks * 32 + kg * 8]);
        acc[m] = mfma16(a, b, acc[m]);
      }
    }
    #pragma unroll
    for (int m = 0; m < 8; ++m)
      #pragma unroll
      for (int r = 0; r < 4; ++r) {
        float x = acc[m][r] + bvv[m];
        Sacc[m][r] += (x > 0.f ? x : 0.01f * x);
      }
  }
  for (int j = 0; j < 8; ++j) {
    f32x4 acc[8];
    #pragma unroll
    for (int m = 0; m < 8; ++m) acc[m] = f32x4{0.f, 0.f, 0.f, 0.f};
    const short* ep = eB + (size_t)(j * 8192 + rowbase + lr) * 128;
    #pragma unroll
    for (int ks = 0; ks < 4; ++ks) {
      short8 a = *(const short8*)(ep + ks * 32 + kg * 8);
      #pragma unroll
      for (int m = 0; m < 8; ++m) {
        short8 b = *(const short8*)(&BW[(m * 16 + lr) * 136 + ks * 32 + kg * 8]);
        acc[m] = mfma16(a, b, acc[m]);
      }
    }
    #pragma unroll
    for (int r = 0; r < 4; ++r) {
      short8 pkt;
      #pragma unroll
      for (int m = 0; m < 8; ++m) {
        float x = acc[m][r] + bvv[m];
        x = (x > 0.f) ? x : 0.01f * x;
        pkt[m] = f2bf(Sacc[m][r] - x);
      }
      *(short8*)(AB + (size_t)(j * 8192 + rowbase + kg * 4 + r) * 1024 +
                 l * 128 + lr * 8) = pkt;
    }
  }
}

__global__ __launch_bounds__(512, 2) void k3_g(const short* __restrict__ eB,
                                               const short* __restrict__ AB,
                                               const short* __restrict__ W1P,
                                               const float* __restrict__ b1,
                                               const float* __restrict__ W2,
                                               const float* __restrict__ b2,
                                               float* __restrict__ out) {
  __shared__ __align__(16) short BW[2][128 * 128];
  const int bid = blockIdx.x;
  const int i = bid & 7;
  const int btile = bid >> 3;
  const int tid = threadIdx.x;
  const int lane = tid & 63, wave = tid >> 6, lr = lane & 15, kg = lane >> 4;
  const int lr8 = lane & 7;
  const int rowbase = btile * 128 + wave * 16;
  const short* w1 = W1P + (size_t)i * 147456;

#define STAGE_W1(buf, koff)                                                    \
  {                                                                            \
    _Pragma("unroll") for (int t = 0; t < 4; ++t) {                            \
      int G = t * 512 + tid;                                                   \
      int cG = G >> 4, gl = G & 15;                                            \
      async_copy16((buf) + (t * 512 + wave * 64) * 8,                          \
                   w1 + cG * 1152 + (koff) + ((gl ^ (cG & 7)) << 3));          \
    }                                                                          \
  }

  const short* abase = AB + (size_t)(i * 8192 + rowbase + lr) * 1024;
  const short* ebase = eB + (size_t)(i * 8192 + rowbase + lr) * 128;

  short8 ea[4], aa[4], aap[4];
  #pragma unroll
  for (int ks = 0; ks < 4; ++ks) {
    ea[ks] = *(const short8*)(ebase + (ks * 4 + kg) * 8);
    aa[ks] = *(const short8*)(abase + (ks * 4 + kg) * 8);
  }
  f32x4 hacc[8];
  #pragma unroll
  for (int m = 0; m < 8; ++m) hacc[m] = f32x4{0.f, 0.f, 0.f, 0.f};

  STAGE_W1(BW[0], 0);
  for (int c = 0; c < 9; ++c) {
    __syncthreads();
    if (c < 8) { STAGE_W1(BW[(c + 1) & 1], (c + 1 == 8) ? 1024 : (c + 1) * 128); }
    if (c + 1 < 8) {
      #pragma unroll
      for (int ks = 0; ks < 4; ++ks)
        aap[ks] = *(const short8*)(abase + (c + 1) * 128 + (ks * 4 + kg) * 8);
    }
    const short* bw = BW[c & 1];
    #pragma unroll
    for (int ks = 0; ks < 4; ++ks)
      #pragma unroll
      for (int m = 0; m < 8; ++m) {
        short8 b = *(const short8*)(bw + (m * 16 + lr) * 128 +
                                    (((ks * 4 + kg) ^ lr8) << 3));
        hacc[m] = mfma16(aa[ks], b, hacc[m]);
      }
    if (c + 1 < 8) {
      #pragma unroll
      for (int ks = 0; ks < 4; ++ks) aa[ks] = aap[ks];
    } else {
      #pragma unroll
      for (int ks = 0; ks < 4; ++ks) aa[ks] = ea[ks];
    }
  }
#undef STAGE_W1

  float sacc[4] = {0.f, 0.f, 0.f, 0.f};
  #pragma unroll
  for (int m = 0; m < 8; ++m) {
    int col = m * 16 + lr;
    float b1v = b1[i * 128 + col];
    float w2v = W2[i * 128 + col];
    #pragma unroll
    for (int r = 0; r < 4; ++r) {
      float h = hacc[m][r] + b1v;
      h = h > 0.f ? h : 0.f;
      sacc[r] += h * w2v;
    }
  }
  #pragma unroll
  for (int r = 0; r < 4; ++r) {
    float v = sacc[r];
    v += __shfl_xor(v, 1);
    v += __shfl_xor(v, 2);
    v += __shfl_xor(v, 4);
    v += __shfl_xor(v, 8);
    if (lr == 0) out[i * 8192 + rowbase + kg * 4 + r] = v + b2[i];
  }
}

extern "C" void kernel_launch(void* const* d_in, const int* in_sizes, int n_in,
                              void* d_out, int out_size, void* d_ws, size_t ws_size,
                              hipStream_t stream) {
  const float* obs = (const float*)d_in[0];
  const float* act = (const float*)d_in[1];
  const float* Wg  = (const float*)d_in[2];
  const float* bg  = (const float*)d_in[3];
  // d_in[4..7] = Wq,bq,Wk,bk: dead (softmax over singleton axis == 1)
  const float* Wv  = (const float*)d_in[8];
  const float* bv  = (const float*)d_in[9];
  const float* W1  = (const float*)d_in[10];
  const float* b1  = (const float*)d_in[11];
  const float* W2  = (const float*)d_in[12];
  const float* b2  = (const float*)d_in[13];
  float* out = (float*)d_out;

  const size_t E_N = (size_t)8 * 8192 * 128;    // eB shorts (8.4M)
  const size_t V_B = (size_t)64 * 8192 * 128;   // VBg BYTES (fp8, 67.1 MB)
  const size_t W_N = 163840 + 131072 + 1179648; // weight shorts
  const size_t NEED_FAST = (E_N + E_N + W_N) * 2 + V_B;  // ~104 MB

  if (ws_size >= NEED_FAST) {
    short* eB  = (short*)d_ws;
    unsigned char* VBg = (unsigned char*)(eB + E_N);
    short* SB  = (short*)(VBg + V_B);
    short* WgT = SB + E_N;
    short* WvP = WgT + 163840;
    short* W1P = WvP + 131072;
    k0_tr<<<720, 256, 0, stream>>>(Wg, Wv, W1, WgT, WvP, W1P);
    k1_e<<<dim3(128, 8), 256, 0, stream>>>(obs, act, WgT, bg, eB);
    k2_V<<<dim3(128, 8), 256, 0, stream>>>(eB, WvP, bv, SB, VBg);
    k3_h<<<512, 512, 0, stream>>>(eB, SB, VBg, W1P, b1, W2, b2, out);
  } else {
    short* eB  = (short*)d_ws;
    short* AB  = eB + E_N;
    short* WgT = AB + (size_t)8 * 8192 * 1024;
    short* WvP = WgT + 163840;
    short* W1P = WvP + 131072;
    k0_tr<<<720, 256, 0, stream>>>(Wg, Wv, W1, WgT, WvP, W1P);
    k1_e<<<dim3(128, 8), 256, 0, stream>>>(obs, act, WgT, bg, eB);
    k2_A<<<dim3(128, 8), 256, 0, stream>>>(eB, WvP, bv, AB);
    k3_g<<<512, 512, 0, stream>>>(eB, AB, W1P, b1, W2, b2, out);
  }
}